// Round 2
// baseline (298.728 us; speedup 1.0000x reference)
//
#include <hip/hip_runtime.h>
#include <math.h>

#define LN10000 9.210340371976184f

// ---- scratch layout (float offsets into workspace) ----
#define OFF_MEAN   0
#define OFF_ISTD   1024
#define OFF_STD    2048
#define OFF_E1     3072              // 32*98*512
#define OFF_SCALE  1608704           // 32*98*32
#define OFF_XC     1709056           // 32*96*512
#define OFF_XM     3281920           // 32*96*512
#define OFF_INWT   4854784           // 4*128*512  [g][j][e]
#define OFF_OUTPT  5116928           // 4*256*128  [g][e][j]
#define OFF_XPWT   5248000           // 4*256*40   [g][e][r]
#define OFF_HETT   5288960           // 512*32     [d][c]
#define OFF_OWT    5305344           // 512*32     [d][c]
#define OFF_CWT    5321728           // 96*512     [c*3+k][d]
#define OFF_TWT    5370880           // 4*512      [m][d]
#define WS_FLOATS  5372928

__device__ float g_fb[WS_FLOATS];    // fallback only if ws_size too small

// ---------------- kernel 0: stats (blocks 0..31) + weight transposes --------
__global__ __launch_bounds__(256) void k_prep(float* S,
                                              const float* __restrict__ x,
                                              const float* __restrict__ in_w,
                                              const float* __restrict__ outp_w,
                                              const float* __restrict__ xp_w,
                                              const float* __restrict__ het_w,
                                              const float* __restrict__ ow,
                                              const float* __restrict__ conv_w,
                                              const float* __restrict__ temp_w) {
    __shared__ float shs[8][32], shq[8][32];
    if (blockIdx.x < 32) {
        int b = blockIdx.x;
        int c = threadIdx.x & 31, r = threadIdx.x >> 5;
        const float* xb = x + (size_t)b * 1024 * 32;
        float s = 0.f, s2 = 0.f;
        for (int l = r; l < 1024; l += 8) {
            float v = xb[l * 32 + c];
            s += v; s2 += v * v;
        }
        shs[r][c] = s; shq[r][c] = s2;
        __syncthreads();
        if (threadIdx.x < 32) {
            float Sm = 0.f, Q = 0.f;
            for (int i = 0; i < 8; i++) { Sm += shs[i][threadIdx.x]; Q += shq[i][threadIdx.x]; }
            float m = Sm * (1.f / 1024.f);
            float var = Q * (1.f / 1024.f) - m * m;
            float sd = sqrtf(var + 1e-5f);
            S[OFF_MEAN + b * 32 + threadIdx.x] = m;
            S[OFF_STD  + b * 32 + threadIdx.x] = sd;
            S[OFF_ISTD + b * 32 + threadIdx.x] = 1.f / sd;
        }
        return;
    }
    int base = (blockIdx.x - 32) * 256 + threadIdx.x;
    const int stride = 128 * 256;
    for (int i = base; i < 4 * 512 * 128; i += stride) {
        int g = i / (512 * 128), rem = i % (512 * 128);
        int e = rem / 128, j = rem % 128;
        S[OFF_INWT + (g * 128 + j) * 512 + e] = in_w[i];
    }
    for (int i = base; i < 4 * 128 * 256; i += stride) {
        int g = i / (128 * 256), rem = i % (128 * 256);
        int j = rem / 256, e = rem % 256;
        S[OFF_OUTPT + (g * 256 + e) * 128 + j] = outp_w[i];
    }
    for (int i = base; i < 4 * 40 * 256; i += stride) {
        int g = i / (40 * 256), rem = i % (40 * 256);
        int r = rem / 256, e = rem % 256;
        S[OFF_XPWT + (g * 256 + e) * 40 + r] = xp_w[i];
    }
    for (int i = base; i < 32 * 512; i += stride) {
        int c = i / 512, d = i % 512;
        S[OFF_HETT + d * 32 + c] = het_w[i];
        S[OFF_OWT  + d * 32 + c] = ow[i];
    }
    for (int i = base; i < 512 * 96; i += stride) {
        int d = i / 96, r = i % 96;
        S[OFF_CWT + r * 512 + d] = conv_w[i];
    }
    for (int i = base; i < 512 * 4; i += stride) {
        int d = i / 4, m = i % 4;
        S[OFF_TWT + m * 512 + d] = temp_w[i];
    }
}

// ---------------- kernel 1: e1 + scale at 98 positions ----------------------
// blockIdx.x = ii (0..97 -> l = 927+ii, ii==97 -> l=0), blockIdx.y = b
__global__ __launch_bounds__(256) void k_e1(float* S,
                                            const float* __restrict__ x_enc,
                                            const float* __restrict__ mark,
                                            const float* __restrict__ het_b) {
    const float* cwT  = S + OFF_CWT;
    const float* twT  = S + OFF_TWT;
    const float* hetT = S + OFF_HETT;
    int ii = blockIdx.x, b = blockIdx.y;
    int l = (ii == 97) ? 0 : (927 + ii);
    int tid = threadIdx.x;
    __shared__ float xsf[96];
    __shared__ float mk[4];
    __shared__ float e1s[512];
    __shared__ float red[8][32];
    if (tid < 96) {
        int k = tid / 32, c = tid % 32;
        int la = l - 1 + k;
        la = (la < 0) ? la + 1024 : ((la >= 1024) ? la - 1024 : la);
        xsf[c * 3 + k] = (x_enc[((size_t)b * 1024 + la) * 32 + c] - S[OFF_MEAN + b * 32 + c]) * S[OFF_ISTD + b * 32 + c];
    }
    if (tid >= 96 && tid < 100) mk[tid - 96] = mark[((size_t)b * 1024 + l) * 4 + (tid - 96)];
    __syncthreads();

    float a0 = 0.f, a1 = 0.f;
    for (int j = 0; j < 96; j++) {
        float xv = xsf[j];
        a0 += xv * cwT[j * 512 + tid];
        a1 += xv * cwT[j * 512 + tid + 256];
    }
    #pragma unroll
    for (int m = 0; m < 4; m++) {
        float mv = mk[m];
        a0 += mv * twT[m * 512 + tid];
        a1 += mv * twT[m * 512 + tid + 256];
    }
    float accs[2] = {a0, a1};
    #pragma unroll
    for (int hh = 0; hh < 2; hh++) {
        int d = tid + hh * 256;
        float dd = (float)(d & ~1);
        float div = __expf(dd * (-LN10000 / 512.f));
        float sv, cv;
        sincosf((float)l * div, &sv, &cv);
        float t = accs[hh] + ((d & 1) ? cv : sv);
        e1s[d] = t;
        S[OFF_E1 + ((size_t)b * 98 + ii) * 512 + d] = t;
    }
    __syncthreads();

    int c = tid & 31, part = tid >> 5;
    float p = 0.f;
    for (int d = part * 64; d < part * 64 + 64; d++) p += e1s[d] * hetT[d * 32 + c];
    red[part][c] = p;
    __syncthreads();
    if (tid < 32) {
        float Sm = het_b[tid];
        for (int i = 0; i < 8; i++) Sm += red[i][tid];
        S[OFF_SCALE + ((size_t)b * 98 + ii) * 32 + tid] = __expf(Sm);
    }
}

// ---------------- kernel 2: xc = e1 + e2 at 96 positions --------------------
// blockIdx.x = s (0..95 -> l = 928+s), blockIdx.y = b
__global__ __launch_bounds__(256) void k_xc(float* S,
                                            const float* __restrict__ x_enc,
                                            const float* __restrict__ mark) {
    const float* cwT = S + OFF_CWT;
    const float* twT = S + OFF_TWT;
    int s = blockIdx.x, b = blockIdx.y;
    int l = 928 + s;
    int tid = threadIdx.x;
    __shared__ float xsf[96];
    __shared__ float mk[4];
    if (tid < 96) {
        int k = tid / 32, c = tid % 32;
        int la = l - 1 + k;
        if (la >= 1024) la -= 1024;
        int idx = (la == 0) ? 97 : (la - 927);
        float xn = (x_enc[((size_t)b * 1024 + la) * 32 + c] - S[OFF_MEAN + b * 32 + c]) * S[OFF_ISTD + b * 32 + c];
        xsf[c * 3 + k] = xn * S[OFF_SCALE + ((size_t)b * 98 + idx) * 32 + c];
    }
    if (tid >= 96 && tid < 100) mk[tid - 96] = mark[((size_t)b * 1024 + l) * 4 + (tid - 96)];
    __syncthreads();

    float a0 = 0.f, a1 = 0.f;
    for (int j = 0; j < 96; j++) {
        float xv = xsf[j];
        a0 += xv * cwT[j * 512 + tid];
        a1 += xv * cwT[j * 512 + tid + 256];
    }
    #pragma unroll
    for (int m = 0; m < 4; m++) {
        float mv = mk[m];
        a0 += mv * twT[m * 512 + tid];
        a1 += mv * twT[m * 512 + tid + 256];
    }
    float accs[2] = {a0, a1};
    #pragma unroll
    for (int hh = 0; hh < 2; hh++) {
        int d = tid + hh * 256;
        float dd = (float)(d & ~1);
        float div = __expf(dd * (-LN10000 / 512.f));
        float sv, cv;
        sincosf((float)l * div, &sv, &cv);
        float t = accs[hh] + ((d & 1) ? cv : sv);
        t += S[OFF_E1 + ((size_t)b * 98 + (l - 927)) * 512 + d];
        S[OFF_XC + ((size_t)b * 96 + s) * 512 + d] = t;
    }
}

// ---------------- kernel 3: mamba per (g, b, patch) -------------------------
#define LSTR 257
__global__ __launch_bounds__(256) void k_mamba(float* S,
                                               const float* __restrict__ conv1_w,
                                               const float* __restrict__ conv1_b,
                                               const float* __restrict__ dt_w,
                                               const float* __restrict__ dt_b,
                                               const float* __restrict__ A_log,
                                               const float* __restrict__ Dp) {
    int p = blockIdx.x, b = blockIdx.y, g = blockIdx.z;
    int tid = threadIdx.x;
    __shared__ float xlds[16 * 128];
    __shared__ float xcv[16 * LSTR];
    __shared__ float zl[16 * LSTR];
    __shared__ float xcn[16 * LSTR];
    __shared__ float dtraw[16 * 8];
    __shared__ float Bmat[16 * 16];
    __shared__ float Cmat[16 * 16];

    for (int i = tid; i < 2048; i += 256) {
        int t = i >> 7, j = i & 127;
        xlds[i] = S[OFF_XC + ((size_t)b * 96 + p * 16 + t) * 512 + g * 128 + j];
    }
    __syncthreads();

    {   // xz = x @ in_w^T
        float a0[16], a1[16];
        #pragma unroll
        for (int t = 0; t < 16; t++) { a0[t] = 0.f; a1[t] = 0.f; }
        const float* W = S + OFF_INWT + (size_t)g * 128 * 512;
        for (int j = 0; j < 128; j++) {
            float w0 = W[j * 512 + tid];
            float w1 = W[j * 512 + tid + 256];
            #pragma unroll
            for (int t = 0; t < 16; t++) {
                float xv = xlds[t * 128 + j];
                a0[t] += xv * w0;
                a1[t] += xv * w1;
            }
        }
        #pragma unroll
        for (int t = 0; t < 16; t++) {
            xcv[t * LSTR + tid] = a0[t];
            zl[t * LSTR + tid] = a1[t];
        }
    }
    __syncthreads();

    {   // depthwise conv(4) + bias + silu
        int e = tid;
        float w0 = conv1_w[(g * 256 + e) * 4 + 0];
        float w1 = conv1_w[(g * 256 + e) * 4 + 1];
        float w2 = conv1_w[(g * 256 + e) * 4 + 2];
        float w3 = conv1_w[(g * 256 + e) * 4 + 3];
        float bb = conv1_b[g * 256 + e];
        #pragma unroll
        for (int t = 0; t < 16; t++) {
            float sa = bb;
            if (t >= 3) sa += xcv[(t - 3) * LSTR + e] * w0;
            if (t >= 2) sa += xcv[(t - 2) * LSTR + e] * w1;
            if (t >= 1) sa += xcv[(t - 1) * LSTR + e] * w2;
            sa += xcv[t * LSTR + e] * w3;
            xcn[t * LSTR + e] = sa * (1.f / (1.f + __expf(-sa)));
        }
    }
    __syncthreads();

    {   // dbl = xconv @ xp_w^T
        const float* XP = S + OFF_XPWT + g * 256 * 40;
        for (int o = tid; o < 640; o += 256) {
            int t = o / 40, r = o % 40;
            float sa = 0.f;
            for (int e = 0; e < 256; e++) sa += xcn[t * LSTR + e] * XP[e * 40 + r];
            if (r < 8) dtraw[t * 8 + r] = sa;
            else if (r < 24) Bmat[t * 16 + (r - 8)] = sa;
            else Cmat[t * 16 + (r - 24)] = sa;
        }
    }
    __syncthreads();

    {   // dt = softplus(dtraw @ dt_w^T + dt_b)
        int e = tid;
        float w[8];
        #pragma unroll
        for (int r = 0; r < 8; r++) w[r] = dt_w[(g * 256 + e) * 8 + r];
        float bb = dt_b[g * 256 + e];
        #pragma unroll
        for (int t = 0; t < 16; t++) {
            float sa = bb;
            #pragma unroll
            for (int r = 0; r < 8; r++) sa += dtraw[t * 8 + r] * w[r];
            float v = (sa > 20.f) ? sa : log1pf(__expf(sa));
            xcv[t * LSTR + e] = v;
        }
    }
    __syncthreads();

    {   // selective scan, y in place into xcn
        int e = tid;
        float Av[16];
        #pragma unroll
        for (int n = 0; n < 16; n++) Av[n] = -__expf(A_log[(g * 256 + e) * 16 + n]);
        float Dv = Dp[g * 256 + e];
        float h[16];
        #pragma unroll
        for (int n = 0; n < 16; n++) h[n] = 0.f;
        for (int t = 0; t < 16; t++) {
            float dtv = xcv[t * LSTR + e];
            float xv = xcn[t * LSTR + e];
            float y = 0.f;
            #pragma unroll
            for (int n = 0; n < 16; n++) {
                h[n] = __expf(dtv * Av[n]) * h[n] + dtv * Bmat[t * 16 + n] * xv;
                y += h[n] * Cmat[t * 16 + n];
            }
            y += Dv * xv;
            float zv = zl[t * LSTR + e];
            y *= zv * (1.f / (1.f + __expf(-zv)));
            xcn[t * LSTR + e] = y;
        }
    }
    __syncthreads();

    {   // out = y @ out_proj_w^T
        int j = tid & 127, th = tid >> 7;
        const float* W = S + OFF_OUTPT + g * 256 * 128;
        float acc[8];
        #pragma unroll
        for (int q = 0; q < 8; q++) acc[q] = 0.f;
        for (int e = 0; e < 256; e++) {
            float w = W[e * 128 + j];
            #pragma unroll
            for (int q = 0; q < 8; q++) acc[q] += xcn[(th * 8 + q) * LSTR + e] * w;
        }
        #pragma unroll
        for (int q = 0; q < 8; q++) {
            int t = th * 8 + q;
            S[OFF_XM + ((size_t)b * 96 + p * 16 + t) * 512 + g * 128 + j] = acc[q];
        }
    }
}

// ---------------- kernel 4: final projection + de-normalize -----------------
__global__ __launch_bounds__(128) void k_out(float* S, float* __restrict__ out) {
    int s = blockIdx.x, b = blockIdx.y;
    int tid = threadIdx.x;
    int c = tid & 31, part = tid >> 5;
    __shared__ float red[4][32];
    const float* xr = S + OFF_XM + ((size_t)b * 96 + s) * 512;
    const float* owT = S + OFF_OWT;
    float p = 0.f;
    for (int d = part * 128; d < part * 128 + 128; d++) p += xr[d] * owT[d * 32 + c];
    red[part][c] = p;
    __syncthreads();
    if (tid < 32) {
        float Sm = red[0][tid] + red[1][tid] + red[2][tid] + red[3][tid];
        out[((size_t)b * 96 + s) * 32 + tid] = Sm * S[OFF_STD + b * 32 + tid] + S[OFF_MEAN + b * 32 + tid];
    }
}

extern "C" void kernel_launch(void* const* d_in, const int* in_sizes, int n_in,
                              void* d_out, int out_size, void* d_ws, size_t ws_size,
                              hipStream_t stream) {
    (void)in_sizes; (void)n_in; (void)out_size;
    const float* x_enc   = (const float*)d_in[0];
    const float* mark    = (const float*)d_in[1];
    const float* conv_w  = (const float*)d_in[4];
    const float* temp_w  = (const float*)d_in[5];
    const float* het_w   = (const float*)d_in[6];
    const float* het_b   = (const float*)d_in[7];
    const float* in_proj = (const float*)d_in[8];
    const float* conv1_w = (const float*)d_in[9];
    const float* conv1_b = (const float*)d_in[10];
    const float* xp_w    = (const float*)d_in[11];
    const float* dt_w    = (const float*)d_in[12];
    const float* dt_b    = (const float*)d_in[13];
    const float* A_log   = (const float*)d_in[14];
    const float* D_param = (const float*)d_in[15];
    const float* outp_w  = (const float*)d_in[16];
    const float* ow      = (const float*)d_in[17];
    float* out = (float*)d_out;

    float* S = (float*)d_ws;
    if (ws_size < (size_t)WS_FLOATS * sizeof(float)) {
        void* p = nullptr;
        hipGetSymbolAddress(&p, HIP_SYMBOL(g_fb));
        S = (float*)p;
    }

    k_prep<<<dim3(160), dim3(256), 0, stream>>>(S, x_enc, in_proj, outp_w, xp_w, het_w, ow, conv_w, temp_w);
    k_e1<<<dim3(98, 32), dim3(256), 0, stream>>>(S, x_enc, mark, het_b);
    k_xc<<<dim3(96, 32), dim3(256), 0, stream>>>(S, x_enc, mark);
    k_mamba<<<dim3(6, 32, 4), dim3(256), 0, stream>>>(S, conv1_w, conv1_b, dt_w, dt_b, A_log, D_param);
    k_out<<<dim3(96, 32), dim3(128), 0, stream>>>(S, out);
}

// Round 3
// 220.566 us; speedup vs baseline: 1.3544x; 1.3544x over previous
//
#include <hip/hip_runtime.h>
#include <math.h>

#define LN10000 9.210340371976184f

// ---- scratch layout (float offsets into workspace) ----
#define OFF_MEAN   0
#define OFF_ISTD   1024
#define OFF_STD    2048
#define OFF_E1     3072              // 32*98*512
#define OFF_SCALE  1608704           // 32*98*32
#define OFF_XC     1709056           // 32*96*512
#define OFF_XM     3281920           // 32*96*512
#define OFF_INWT   4854784           // 4*128*512  [g][j][2e+h]  (pairs E=e / E=e+256)
#define OFF_OUTPT  5116928           // 4*256*128  [g][e][j]
#define OFF_XPWT   5248000           // 4*256*40   [g][e][r]
#define OFF_HETT   5288960           // 512*32     [d][c]
#define OFF_OWT    5305344           // 512*32     [d][c]
#define OFF_CWT    5321728           // 96*512     [c*3+k][d]
#define OFF_TWT    5370880           // 4*512      [m][d]
#define OFF_PE     5372928           // 98*512     [ii][d]
#define OFF_A2T    5423104           // 4*16*256   [g][n][e] = -exp(A_log)
#define OFF_CW1T   5439488           // 4*1024     [k][g*256+e]
#define OFF_DTWT   5443584           // 8*1024     [r][g*256+e]
#define WS_FLOATS  5451776

__device__ float g_fb[WS_FLOATS];    // fallback only if ws_size too small

// ---------------- kernel 0: stats (blocks 0..31) + weight prep --------------
__global__ __launch_bounds__(256) void k_prep(float* S,
                                              const float* __restrict__ x,
                                              const float* __restrict__ in_w,
                                              const float* __restrict__ outp_w,
                                              const float* __restrict__ xp_w,
                                              const float* __restrict__ het_w,
                                              const float* __restrict__ ow,
                                              const float* __restrict__ conv_w,
                                              const float* __restrict__ temp_w,
                                              const float* __restrict__ A_log,
                                              const float* __restrict__ conv1_w,
                                              const float* __restrict__ dt_w) {
    __shared__ float shs[8][32], shq[8][32];
    if (blockIdx.x < 32) {
        int b = blockIdx.x;
        int c = threadIdx.x & 31, r = threadIdx.x >> 5;
        const float* xb = x + (size_t)b * 1024 * 32;
        float s = 0.f, s2 = 0.f;
        for (int l = r; l < 1024; l += 8) {
            float v = xb[l * 32 + c];
            s += v; s2 += v * v;
        }
        shs[r][c] = s; shq[r][c] = s2;
        __syncthreads();
        if (threadIdx.x < 32) {
            float Sm = 0.f, Q = 0.f;
            for (int i = 0; i < 8; i++) { Sm += shs[i][threadIdx.x]; Q += shq[i][threadIdx.x]; }
            float m = Sm * (1.f / 1024.f);
            float var = Q * (1.f / 1024.f) - m * m;
            float sd = sqrtf(var + 1e-5f);
            S[OFF_MEAN + b * 32 + threadIdx.x] = m;
            S[OFF_STD  + b * 32 + threadIdx.x] = sd;
            S[OFF_ISTD + b * 32 + threadIdx.x] = 1.f / sd;
        }
        return;
    }
    int base = (blockIdx.x - 32) * 256 + threadIdx.x;
    const int stride = 128 * 256;
    // in_proj: [g][E][j] -> pairs [g][j][2e+h], h: E=e / E=e+256
    for (int i = base; i < 4 * 512 * 128; i += stride) {
        int g = i >> 16, rem = i & 65535;
        int j = rem >> 9, u = rem & 511;
        int e = u >> 1, h = u & 1;
        S[OFF_INWT + i] = in_w[((size_t)(g * 512 + h * 256 + e)) * 128 + j];
    }
    for (int i = base; i < 4 * 128 * 256; i += stride) {
        int g = i / (128 * 256), rem = i % (128 * 256);
        int j = rem / 256, e = rem % 256;
        S[OFF_OUTPT + (g * 256 + e) * 128 + j] = outp_w[i];
    }
    for (int i = base; i < 4 * 40 * 256; i += stride) {
        int g = i / (40 * 256), rem = i % (40 * 256);
        int r = rem / 256, e = rem % 256;
        S[OFF_XPWT + (g * 256 + e) * 40 + r] = xp_w[i];
    }
    for (int i = base; i < 32 * 512; i += stride) {
        int c = i / 512, d = i % 512;
        S[OFF_HETT + d * 32 + c] = het_w[i];
        S[OFF_OWT  + d * 32 + c] = ow[i];
    }
    for (int i = base; i < 512 * 96; i += stride) {
        int d = i / 96, r = i % 96;
        S[OFF_CWT + r * 512 + d] = conv_w[i];
    }
    for (int i = base; i < 512 * 4; i += stride) {
        int d = i / 4, m = i % 4;
        S[OFF_TWT + m * 512 + d] = temp_w[i];
    }
    // PE table: ii 0..96 -> l=927+ii ; ii=97 -> l=0
    for (int i = base; i < 98 * 256; i += stride) {
        int ii = i >> 8, q = i & 255;
        int l = (ii == 97) ? 0 : (927 + ii);
        float div = __expf((float)(2 * q) * (-LN10000 / 512.f));
        float sv, cv;
        sincosf((float)l * div, &sv, &cv);
        S[OFF_PE + ii * 512 + 2 * q]     = sv;
        S[OFF_PE + ii * 512 + 2 * q + 1] = cv;
    }
    // A2T = -exp(A_log), [g][n][e]
    for (int i = base; i < 4 * 16 * 256; i += stride) {
        int g = i >> 12, n = (i >> 8) & 15, e = i & 255;
        S[OFF_A2T + i] = -__expf(A_log[(g * 256 + e) * 16 + n]);
    }
    for (int i = base; i < 4 * 1024; i += stride) {
        int k = i >> 10, ge = i & 1023;
        S[OFF_CW1T + i] = conv1_w[ge * 4 + k];
    }
    for (int i = base; i < 8 * 1024; i += stride) {
        int r = i >> 10, ge = i & 1023;
        S[OFF_DTWT + i] = dt_w[ge * 8 + r];
    }
}

// ---------------- kernel 1: e1 + scale at 98 positions ----------------------
__global__ __launch_bounds__(256) void k_e1(float* S,
                                            const float* __restrict__ x_enc,
                                            const float* __restrict__ mark,
                                            const float* __restrict__ het_b) {
    int ii = blockIdx.x, b = blockIdx.y;
    int l = (ii == 97) ? 0 : (927 + ii);
    int tid = threadIdx.x;
    __shared__ __align__(16) float xsf[96];
    __shared__ float mk[4];
    __shared__ __align__(16) float e1s[512];
    __shared__ float red[8][32];
    if (tid < 96) {
        int k = tid / 32, c = tid % 32;
        int la = l - 1 + k;
        la = (la < 0) ? la + 1024 : ((la >= 1024) ? la - 1024 : la);
        xsf[c * 3 + k] = (x_enc[((size_t)b * 1024 + la) * 32 + c] - S[OFF_MEAN + b * 32 + c]) * S[OFF_ISTD + b * 32 + c];
    }
    if (tid >= 96 && tid < 100) mk[tid - 96] = mark[((size_t)b * 1024 + l) * 4 + (tid - 96)];
    __syncthreads();

    const float2* cw2 = (const float2*)(S + OFF_CWT);
    const float2* tw2 = (const float2*)(S + OFF_TWT);
    const float2* pe2 = (const float2*)(S + OFF_PE);
    const float4* xs4 = (const float4*)xsf;
    float a0 = 0.f, a1 = 0.f;
    #pragma unroll 4
    for (int j4 = 0; j4 < 24; j4++) {
        float4 xv = xs4[j4];
        float2 w0 = cw2[(j4 * 4 + 0) * 256 + tid];
        float2 w1 = cw2[(j4 * 4 + 1) * 256 + tid];
        float2 w2 = cw2[(j4 * 4 + 2) * 256 + tid];
        float2 w3 = cw2[(j4 * 4 + 3) * 256 + tid];
        a0 += xv.x * w0.x + xv.y * w1.x + xv.z * w2.x + xv.w * w3.x;
        a1 += xv.x * w0.y + xv.y * w1.y + xv.z * w2.y + xv.w * w3.y;
    }
    #pragma unroll
    for (int m = 0; m < 4; m++) {
        float2 w = tw2[m * 256 + tid];
        a0 += mk[m] * w.x;
        a1 += mk[m] * w.y;
    }
    float2 pe = pe2[ii * 256 + tid];
    float t0 = a0 + pe.x, t1 = a1 + pe.y;
    e1s[2 * tid] = t0; e1s[2 * tid + 1] = t1;
    float2 e1o; e1o.x = t0; e1o.y = t1;
    ((float2*)(S + OFF_E1))[((size_t)b * 98 + ii) * 256 + tid] = e1o;
    __syncthreads();

    int c = tid & 31, part = tid >> 5;
    const float* hetT = S + OFF_HETT;
    float p = 0.f;
    for (int d = part * 64; d < part * 64 + 64; d++) p += e1s[d] * hetT[d * 32 + c];
    red[part][c] = p;
    __syncthreads();
    if (tid < 32) {
        float Sm = het_b[tid];
        for (int i = 0; i < 8; i++) Sm += red[i][tid];
        S[OFF_SCALE + ((size_t)b * 98 + ii) * 32 + tid] = __expf(Sm);
    }
}

// ---------------- kernel 2: xc = e1 + e2 at 96 positions --------------------
__global__ __launch_bounds__(256) void k_xc(float* S,
                                            const float* __restrict__ x_enc,
                                            const float* __restrict__ mark) {
    int s = blockIdx.x, b = blockIdx.y;
    int l = 928 + s;
    int tid = threadIdx.x;
    __shared__ __align__(16) float xsf[96];
    __shared__ float mk[4];
    if (tid < 96) {
        int k = tid / 32, c = tid % 32;
        int la = l - 1 + k;
        if (la >= 1024) la -= 1024;
        int idx = (la == 0) ? 97 : (la - 927);
        float xn = (x_enc[((size_t)b * 1024 + la) * 32 + c] - S[OFF_MEAN + b * 32 + c]) * S[OFF_ISTD + b * 32 + c];
        xsf[c * 3 + k] = xn * S[OFF_SCALE + ((size_t)b * 98 + idx) * 32 + c];
    }
    if (tid >= 96 && tid < 100) mk[tid - 96] = mark[((size_t)b * 1024 + l) * 4 + (tid - 96)];
    __syncthreads();

    const float2* cw2 = (const float2*)(S + OFF_CWT);
    const float2* tw2 = (const float2*)(S + OFF_TWT);
    const float2* pe2 = (const float2*)(S + OFF_PE);
    const float4* xs4 = (const float4*)xsf;
    float a0 = 0.f, a1 = 0.f;
    #pragma unroll 4
    for (int j4 = 0; j4 < 24; j4++) {
        float4 xv = xs4[j4];
        float2 w0 = cw2[(j4 * 4 + 0) * 256 + tid];
        float2 w1 = cw2[(j4 * 4 + 1) * 256 + tid];
        float2 w2 = cw2[(j4 * 4 + 2) * 256 + tid];
        float2 w3 = cw2[(j4 * 4 + 3) * 256 + tid];
        a0 += xv.x * w0.x + xv.y * w1.x + xv.z * w2.x + xv.w * w3.x;
        a1 += xv.x * w0.y + xv.y * w1.y + xv.z * w2.y + xv.w * w3.y;
    }
    #pragma unroll
    for (int m = 0; m < 4; m++) {
        float2 w = tw2[m * 256 + tid];
        a0 += mk[m] * w.x;
        a1 += mk[m] * w.y;
    }
    float2 pe = pe2[(s + 1) * 256 + tid];
    float2 e1v = ((const float2*)(S + OFF_E1))[((size_t)b * 98 + (s + 1)) * 256 + tid];
    float2 o;
    o.x = a0 + pe.x + e1v.x;
    o.y = a1 + pe.y + e1v.y;
    ((float2*)(S + OFF_XC))[((size_t)b * 96 + s) * 256 + tid] = o;
}

// ---------------- kernel 3: mamba per (g, b, patch) -------------------------
#define PADX 20
#define PADE 20
__global__ __launch_bounds__(256, 4) void k_mamba(float* S,
                                                  const float* __restrict__ conv1_b,
                                                  const float* __restrict__ dt_b,
                                                  const float* __restrict__ Dp) {
    int p = blockIdx.x, b = blockIdx.y, g = blockIdx.z;
    int tid = threadIdx.x;
    __shared__ __align__(16) float xT[128 * PADX];    // x tile transposed [j][t]
    __shared__ __align__(16) float ycT[256 * PADE];   // conv-out then y, [e][t]
    __shared__ __align__(16) float dtraw[16 * 8];
    __shared__ float Bm[16 * 16];
    __shared__ float Cm[16 * 16];

    // A: load tile + transpose into LDS
    {
        const float* xg = S + OFF_XC + ((size_t)b * 96 + p * 16) * 512 + g * 128;
        #pragma unroll
        for (int it = 0; it < 8; it++) {
            int i = it * 256 + tid;
            int t = i >> 7, j = i & 127;
            xT[j * PADX + t] = xg[t * 512 + j];
        }
    }
    __syncthreads();

    // B: in-proj -> a0 (x-branch), z (gate) in registers
    float a0[16], z[16];
    #pragma unroll
    for (int t = 0; t < 16; t++) { a0[t] = 0.f; z[t] = 0.f; }
    {
        const float2* W2 = (const float2*)(S + OFF_INWT) + (size_t)g * 128 * 256 + tid;
        for (int j = 0; j < 128; j++) {
            float2 w = W2[j * 256];
            const float4* xr = (const float4*)&xT[j * PADX];
            float4 x0 = xr[0], x1 = xr[1], x2 = xr[2], x3 = xr[3];
            a0[0]  += x0.x * w.x; z[0]  += x0.x * w.y;
            a0[1]  += x0.y * w.x; z[1]  += x0.y * w.y;
            a0[2]  += x0.z * w.x; z[2]  += x0.z * w.y;
            a0[3]  += x0.w * w.x; z[3]  += x0.w * w.y;
            a0[4]  += x1.x * w.x; z[4]  += x1.x * w.y;
            a0[5]  += x1.y * w.x; z[5]  += x1.y * w.y;
            a0[6]  += x1.z * w.x; z[6]  += x1.z * w.y;
            a0[7]  += x1.w * w.x; z[7]  += x1.w * w.y;
            a0[8]  += x2.x * w.x; z[8]  += x2.x * w.y;
            a0[9]  += x2.y * w.x; z[9]  += x2.y * w.y;
            a0[10] += x2.z * w.x; z[10] += x2.z * w.y;
            a0[11] += x2.w * w.x; z[11] += x2.w * w.y;
            a0[12] += x3.x * w.x; z[12] += x3.x * w.y;
            a0[13] += x3.y * w.x; z[13] += x3.y * w.y;
            a0[14] += x3.z * w.x; z[14] += x3.z * w.y;
            a0[15] += x3.w * w.x; z[15] += x3.w * w.y;
        }
    }
    __syncthreads();   // xT free after this (not reused)

    // C: depthwise conv(4) + silu, all in registers; publish to ycT
    float xq[16];
    {
        int ge = g * 256 + tid;
        float w0 = S[OFF_CW1T + 0 * 1024 + ge];
        float w1 = S[OFF_CW1T + 1 * 1024 + ge];
        float w2 = S[OFF_CW1T + 2 * 1024 + ge];
        float w3 = S[OFF_CW1T + 3 * 1024 + ge];
        float bb = conv1_b[ge];
        #pragma unroll
        for (int t = 0; t < 16; t++) {
            float sa = bb + w3 * a0[t];
            if (t >= 1) sa += w2 * a0[t - 1];
            if (t >= 2) sa += w1 * a0[t - 2];
            if (t >= 3) sa += w0 * a0[t - 3];
            xq[t] = sa * (1.f / (1.f + __expf(-sa)));
        }
        float4* yr = (float4*)&ycT[tid * PADE];
        yr[0] = make_float4(xq[0], xq[1], xq[2], xq[3]);
        yr[1] = make_float4(xq[4], xq[5], xq[6], xq[7]);
        yr[2] = make_float4(xq[8], xq[9], xq[10], xq[11]);
        yr[3] = make_float4(xq[12], xq[13], xq[14], xq[15]);
    }
    __syncthreads();

    // D: x-proj (640 outputs)
    {
        const float* XPb = S + OFF_XPWT + g * 256 * 40;
        for (int o = tid; o < 640; o += 256) {
            int t = o / 40, r = o - t * 40;
            const float* XP = XPb + r;
            float sa = 0.f;
            for (int e = 0; e < 256; e++) sa += ycT[e * PADE + t] * XP[e * 40];
            if (r < 8) dtraw[t * 8 + r] = sa;
            else if (r < 24) Bm[t * 16 + (r - 8)] = sa;
            else Cm[t * 16 + (r - 24)] = sa;
        }
    }
    __syncthreads();

    // E+F: dt + selective scan, per-channel in registers; y -> ycT (overwrite)
    {
        int ge = g * 256 + tid;
        float Av[16];
        #pragma unroll
        for (int n = 0; n < 16; n++) Av[n] = S[OFF_A2T + (g * 16 + n) * 256 + tid];
        float dtw[8];
        #pragma unroll
        for (int r = 0; r < 8; r++) dtw[r] = S[OFF_DTWT + r * 1024 + ge];
        float dtbv = dt_b[ge];
        float Dv = Dp[ge];
        float h[16];
        #pragma unroll
        for (int n = 0; n < 16; n++) h[n] = 0.f;
        for (int t = 0; t < 16; t++) {
            const float4* q = (const float4*)&dtraw[t * 8];
            float4 q0 = q[0], q1 = q[1];
            float sa = dtbv + q0.x * dtw[0] + q0.y * dtw[1] + q0.z * dtw[2] + q0.w * dtw[3]
                            + q1.x * dtw[4] + q1.y * dtw[5] + q1.z * dtw[6] + q1.w * dtw[7];
            float dtv = (sa > 20.f) ? sa : log1pf(__expf(sa));
            float xv = xq[t];
            float dx = dtv * xv;
            float y = 0.f;
            #pragma unroll
            for (int n = 0; n < 16; n++) {
                h[n] = __expf(dtv * Av[n]) * h[n] + dx * Bm[t * 16 + n];
                y += h[n] * Cm[t * 16 + n];
            }
            y += Dv * xv;
            float zv = z[t];
            y *= zv * (1.f / (1.f + __expf(-zv)));
            ycT[tid * PADE + t] = y;
        }
    }
    __syncthreads();

    // G: out-proj
    {
        int j = tid & 127, th = tid >> 7;
        const float* WO = S + OFF_OUTPT + g * 256 * 128 + j;
        float acc[8];
        #pragma unroll
        for (int q = 0; q < 8; q++) acc[q] = 0.f;
        for (int e = 0; e < 256; e++) {
            float w = WO[e * 128];
            const float4* yr = (const float4*)&ycT[e * PADE + th * 8];
            float4 y0 = yr[0], y1 = yr[1];
            acc[0] += y0.x * w; acc[1] += y0.y * w;
            acc[2] += y0.z * w; acc[3] += y0.w * w;
            acc[4] += y1.x * w; acc[5] += y1.y * w;
            acc[6] += y1.z * w; acc[7] += y1.w * w;
        }
        float* XM = S + OFF_XM + ((size_t)b * 96 + p * 16 + th * 8) * 512 + g * 128 + j;
        #pragma unroll
        for (int q = 0; q < 8; q++) XM[q * 512] = acc[q];
    }
}

// ---------------- kernel 4: final projection + de-normalize -----------------
__global__ __launch_bounds__(128) void k_out(float* S, float* __restrict__ out) {
    int s = blockIdx.x, b = blockIdx.y;
    int tid = threadIdx.x;
    int c = tid & 31, part = tid >> 5;
    __shared__ float red[4][32];
    const float* xr = S + OFF_XM + ((size_t)b * 96 + s) * 512;
    const float* owT = S + OFF_OWT;
    float p = 0.f;
    for (int d = part * 128; d < part * 128 + 128; d++) p += xr[d] * owT[d * 32 + c];
    red[part][c] = p;
    __syncthreads();
    if (tid < 32) {
        float Sm = red[0][tid] + red[1][tid] + red[2][tid] + red[3][tid];
        out[((size_t)b * 96 + s) * 32 + tid] = Sm * S[OFF_STD + b * 32 + tid] + S[OFF_MEAN + b * 32 + tid];
    }
}

extern "C" void kernel_launch(void* const* d_in, const int* in_sizes, int n_in,
                              void* d_out, int out_size, void* d_ws, size_t ws_size,
                              hipStream_t stream) {
    (void)in_sizes; (void)n_in; (void)out_size;
    const float* x_enc   = (const float*)d_in[0];
    const float* mark    = (const float*)d_in[1];
    const float* conv_w  = (const float*)d_in[4];
    const float* temp_w  = (const float*)d_in[5];
    const float* het_w   = (const float*)d_in[6];
    const float* het_b   = (const float*)d_in[7];
    const float* in_proj = (const float*)d_in[8];
    const float* conv1_w = (const float*)d_in[9];
    const float* conv1_b = (const float*)d_in[10];
    const float* xp_w    = (const float*)d_in[11];
    const float* dt_w    = (const float*)d_in[12];
    const float* dt_b    = (const float*)d_in[13];
    const float* A_log   = (const float*)d_in[14];
    const float* D_param = (const float*)d_in[15];
    const float* outp_w  = (const float*)d_in[16];
    const float* ow      = (const float*)d_in[17];
    float* out = (float*)d_out;

    float* S = (float*)d_ws;
    if (ws_size < (size_t)WS_FLOATS * sizeof(float)) {
        void* p = nullptr;
        hipGetSymbolAddress(&p, HIP_SYMBOL(g_fb));
        S = (float*)p;
    }

    k_prep<<<dim3(160), dim3(256), 0, stream>>>(S, x_enc, in_proj, outp_w, xp_w, het_w, ow,
                                                conv_w, temp_w, A_log, conv1_w, dt_w);
    k_e1<<<dim3(98, 32), dim3(256), 0, stream>>>(S, x_enc, mark, het_b);
    k_xc<<<dim3(96, 32), dim3(256), 0, stream>>>(S, x_enc, mark);
    k_mamba<<<dim3(6, 32, 4), dim3(256), 0, stream>>>(S, conv1_b, dt_b, D_param);
    k_out<<<dim3(96, 32), dim3(128), 0, stream>>>(S, out);
}

// Round 4
// 179.731 us; speedup vs baseline: 1.6621x; 1.2272x over previous
//
#include <hip/hip_runtime.h>
#include <hip/hip_bf16.h>
#include <math.h>

#define LN10000 9.210340371976184f

typedef __attribute__((ext_vector_type(8))) short short8;
typedef __attribute__((ext_vector_type(4))) float float4v;

// ---- scratch layout (float offsets into workspace) ----
#define OFF_MEAN   0
#define OFF_ISTD   1024
#define OFF_STD    2048
#define OFF_E1     3072              // 32*98*512
#define OFF_SCALE  1608704           // 32*98*32
#define OFF_XC     1709056           // 32*96*512
#define OFF_XM     3281920           // 32*96*512
#define OFF_WIN    4854784           // in-proj frags: 4g*32nt*4ks*2hl*512 ushort = 262144 fl
#define OFF_WXP    5116928           // x-proj frags: 4g*3nt*8ks*512 ushort = 24576 fl
#define OFF_WOUT   5141504           // out-proj frags: 4g*8nt*8ks*512 ushort = 65536 fl
#define OFF_HETT   5207040           // 512*32 [d][c]
#define OFF_OWT    5223424           // 512*32 [d][c]
#define OFF_CWT    5239808           // 96*512 [c*3+k][d]
#define OFF_TWT    5288960           // 4*512  [m][d]
#define OFF_PE     5291008           // 98*512 [ii][d]
#define OFF_A2T    5341184           // 4*16*256 [g][n][e] = -exp(A_log)
#define OFF_CW1T   5357568           // 4*1024 [k][g*256+e]
#define OFF_DTWT   5361664           // 8*1024 [r][g*256+e]
#define WS_FLOATS  5369856

__device__ float g_fb[WS_FLOATS];    // fallback if ws_size too small

__device__ inline short f2bf(float x) {
    __hip_bfloat16 h = __float2bfloat16(x);
    return *reinterpret_cast<short*>(&h);
}
__device__ inline float bf2f_s(short s) {
    __hip_bfloat16 h = *reinterpret_cast<__hip_bfloat16*>(&s);
    return __bfloat162float(h);
}

// ---------------- kernel 0: stats (blocks 0..31) + weight prep/pack ---------
__global__ __launch_bounds__(256) void k_prep(float* S,
                                              const float* __restrict__ x,
                                              const float* __restrict__ in_w,
                                              const float* __restrict__ outp_w,
                                              const float* __restrict__ xp_w,
                                              const float* __restrict__ het_w,
                                              const float* __restrict__ ow,
                                              const float* __restrict__ conv_w,
                                              const float* __restrict__ temp_w,
                                              const float* __restrict__ A_log,
                                              const float* __restrict__ conv1_w,
                                              const float* __restrict__ dt_w) {
    __shared__ float shs[8][32], shq[8][32];
    if (blockIdx.x < 32) {
        int b = blockIdx.x;
        int c = threadIdx.x & 31, r = threadIdx.x >> 5;
        const float* xb = x + (size_t)b * 1024 * 32;
        float s = 0.f, s2 = 0.f;
        for (int l = r; l < 1024; l += 8) {
            float v = xb[l * 32 + c];
            s += v; s2 += v * v;
        }
        shs[r][c] = s; shq[r][c] = s2;
        __syncthreads();
        if (threadIdx.x < 32) {
            float Sm = 0.f, Q = 0.f;
            for (int i = 0; i < 8; i++) { Sm += shs[i][threadIdx.x]; Q += shq[i][threadIdx.x]; }
            float m = Sm * (1.f / 1024.f);
            float var = Q * (1.f / 1024.f) - m * m;
            float sd = sqrtf(var + 1e-5f);
            S[OFF_MEAN + b * 32 + threadIdx.x] = m;
            S[OFF_STD  + b * 32 + threadIdx.x] = sd;
            S[OFF_ISTD + b * 32 + threadIdx.x] = 1.f / sd;
        }
        return;
    }
    int base = (blockIdx.x - 32) * 256 + threadIdx.x;
    const int stride = 128 * 256;

    // in-proj fragments, hi+lo: u = ((((g*32+nt)*4+ks)*2+hl)*64+lane)*8+i
    {
        short* WIN = (short*)(void*)(S + OFF_WIN);
        for (int u = base; u < 4 * 32 * 4 * 2 * 512; u += stride) {
            int g = u >> 17;
            int nt = (u >> 12) & 31;
            int ks = (u >> 10) & 3;
            int hl = (u >> 9) & 1;
            int lane = (u >> 3) & 63;
            int i = u & 7;
            int n = nt * 16 + (lane & 15);
            int k = ks * 32 + (lane >> 4) * 8 + i;
            float v = in_w[((size_t)(g * 512 + n)) * 128 + k];
            short hi = f2bf(v);
            if (hl == 0) WIN[u] = hi;
            else WIN[u] = f2bf(v - bf2f_s(hi));
        }
    }
    // x-proj fragments, hi only: u = (((g*3+nt)*8+ks)*64+lane)*8+i
    {
        short* WXP = (short*)(void*)(S + OFF_WXP);
        for (int u = base; u < 4 * 3 * 8 * 512; u += stride) {
            int i = u & 7;
            int lane = (u >> 3) & 63;
            int ks = (u >> 9) & 7;
            int rest = u >> 12;
            int g = rest / 3, nt = rest % 3;
            int r = nt * 16 + (lane & 15);
            int e = ks * 32 + (lane >> 4) * 8 + i;
            float v = (r < 40) ? xp_w[(g * 40 + r) * 256 + e] : 0.f;
            WXP[u] = f2bf(v);
        }
    }
    // out-proj fragments, hi only: u = (((g*8+nt)*8+ks)*64+lane)*8+i
    {
        short* WOUT = (short*)(void*)(S + OFF_WOUT);
        for (int u = base; u < 4 * 8 * 8 * 512; u += stride) {
            int i = u & 7;
            int lane = (u >> 3) & 63;
            int ks = (u >> 9) & 7;
            int nt = (u >> 12) & 7;
            int g = u >> 15;
            int j = nt * 16 + (lane & 15);
            int e = ks * 32 + (lane >> 4) * 8 + i;
            WOUT[u] = f2bf(outp_w[(g * 128 + j) * 256 + e]);
        }
    }
    for (int i = base; i < 32 * 512; i += stride) {
        int c = i / 512, d = i % 512;
        S[OFF_HETT + d * 32 + c] = het_w[i];
        S[OFF_OWT  + d * 32 + c] = ow[i];
    }
    for (int i = base; i < 512 * 96; i += stride) {
        int d = i / 96, r = i % 96;
        S[OFF_CWT + r * 512 + d] = conv_w[i];
    }
    for (int i = base; i < 512 * 4; i += stride) {
        int d = i / 4, m = i % 4;
        S[OFF_TWT + m * 512 + d] = temp_w[i];
    }
    for (int i = base; i < 98 * 256; i += stride) {
        int ii = i >> 8, q = i & 255;
        int l = (ii == 97) ? 0 : (927 + ii);
        float div = __expf((float)(2 * q) * (-LN10000 / 512.f));
        float sv, cv;
        sincosf((float)l * div, &sv, &cv);
        S[OFF_PE + ii * 512 + 2 * q]     = sv;
        S[OFF_PE + ii * 512 + 2 * q + 1] = cv;
    }
    for (int i = base; i < 4 * 16 * 256; i += stride) {
        int g = i >> 12, n = (i >> 8) & 15, e = i & 255;
        S[OFF_A2T + i] = -__expf(A_log[(g * 256 + e) * 16 + n]);
    }
    for (int i = base; i < 4 * 1024; i += stride) {
        int k = i >> 10, ge = i & 1023;
        S[OFF_CW1T + i] = conv1_w[ge * 4 + k];
    }
    for (int i = base; i < 8 * 1024; i += stride) {
        int r = i >> 10, ge = i & 1023;
        S[OFF_DTWT + i] = dt_w[ge * 8 + r];
    }
}

// ---------------- kernel 1: e1 + scale at 98 positions ----------------------
__global__ __launch_bounds__(256) void k_e1(float* S,
                                            const float* __restrict__ x_enc,
                                            const float* __restrict__ mark,
                                            const float* __restrict__ het_b) {
    int ii = blockIdx.x, b = blockIdx.y;
    int l = (ii == 97) ? 0 : (927 + ii);
    int tid = threadIdx.x;
    __shared__ __align__(16) float xsf[96];
    __shared__ float mk[4];
    __shared__ __align__(16) float e1s[512];
    __shared__ float red[8][32];
    if (tid < 96) {
        int k = tid / 32, c = tid % 32;
        int la = l - 1 + k;
        la = (la < 0) ? la + 1024 : ((la >= 1024) ? la - 1024 : la);
        xsf[c * 3 + k] = (x_enc[((size_t)b * 1024 + la) * 32 + c] - S[OFF_MEAN + b * 32 + c]) * S[OFF_ISTD + b * 32 + c];
    }
    if (tid >= 96 && tid < 100) mk[tid - 96] = mark[((size_t)b * 1024 + l) * 4 + (tid - 96)];
    __syncthreads();

    const float2* cw2 = (const float2*)(S + OFF_CWT);
    const float2* tw2 = (const float2*)(S + OFF_TWT);
    const float2* pe2 = (const float2*)(S + OFF_PE);
    const float4* xs4 = (const float4*)xsf;
    float a0 = 0.f, a1 = 0.f;
    #pragma unroll 4
    for (int j4 = 0; j4 < 24; j4++) {
        float4 xv = xs4[j4];
        float2 w0 = cw2[(j4 * 4 + 0) * 256 + tid];
        float2 w1 = cw2[(j4 * 4 + 1) * 256 + tid];
        float2 w2 = cw2[(j4 * 4 + 2) * 256 + tid];
        float2 w3 = cw2[(j4 * 4 + 3) * 256 + tid];
        a0 += xv.x * w0.x + xv.y * w1.x + xv.z * w2.x + xv.w * w3.x;
        a1 += xv.x * w0.y + xv.y * w1.y + xv.z * w2.y + xv.w * w3.y;
    }
    #pragma unroll
    for (int m = 0; m < 4; m++) {
        float2 w = tw2[m * 256 + tid];
        a0 += mk[m] * w.x;
        a1 += mk[m] * w.y;
    }
    float2 pe = pe2[ii * 256 + tid];
    float t0 = a0 + pe.x, t1 = a1 + pe.y;
    e1s[2 * tid] = t0; e1s[2 * tid + 1] = t1;
    float2 e1o; e1o.x = t0; e1o.y = t1;
    ((float2*)(S + OFF_E1))[((size_t)b * 98 + ii) * 256 + tid] = e1o;
    __syncthreads();

    int c = tid & 31, part = tid >> 5;
    const float* hetT = S + OFF_HETT;
    float p = 0.f;
    for (int d = part * 64; d < part * 64 + 64; d++) p += e1s[d] * hetT[d * 32 + c];
    red[part][c] = p;
    __syncthreads();
    if (tid < 32) {
        float Sm = het_b[tid];
        for (int i = 0; i < 8; i++) Sm += red[i][tid];
        S[OFF_SCALE + ((size_t)b * 98 + ii) * 32 + tid] = __expf(Sm);
    }
}

// ---------------- kernel 2: xc = e1 + e2 at 96 positions --------------------
__global__ __launch_bounds__(256) void k_xc(float* S,
                                            const float* __restrict__ x_enc,
                                            const float* __restrict__ mark) {
    int s = blockIdx.x, b = blockIdx.y;
    int l = 928 + s;
    int tid = threadIdx.x;
    __shared__ __align__(16) float xsf[96];
    __shared__ float mk[4];
    if (tid < 96) {
        int k = tid / 32, c = tid % 32;
        int la = l - 1 + k;
        if (la >= 1024) la -= 1024;
        int idx = (la == 0) ? 97 : (la - 927);
        float xn = (x_enc[((size_t)b * 1024 + la) * 32 + c] - S[OFF_MEAN + b * 32 + c]) * S[OFF_ISTD + b * 32 + c];
        xsf[c * 3 + k] = xn * S[OFF_SCALE + ((size_t)b * 98 + idx) * 32 + c];
    }
    if (tid >= 96 && tid < 100) mk[tid - 96] = mark[((size_t)b * 1024 + l) * 4 + (tid - 96)];
    __syncthreads();

    const float2* cw2 = (const float2*)(S + OFF_CWT);
    const float2* tw2 = (const float2*)(S + OFF_TWT);
    const float2* pe2 = (const float2*)(S + OFF_PE);
    const float4* xs4 = (const float4*)xsf;
    float a0 = 0.f, a1 = 0.f;
    #pragma unroll 4
    for (int j4 = 0; j4 < 24; j4++) {
        float4 xv = xs4[j4];
        float2 w0 = cw2[(j4 * 4 + 0) * 256 + tid];
        float2 w1 = cw2[(j4 * 4 + 1) * 256 + tid];
        float2 w2 = cw2[(j4 * 4 + 2) * 256 + tid];
        float2 w3 = cw2[(j4 * 4 + 3) * 256 + tid];
        a0 += xv.x * w0.x + xv.y * w1.x + xv.z * w2.x + xv.w * w3.x;
        a1 += xv.x * w0.y + xv.y * w1.y + xv.z * w2.y + xv.w * w3.y;
    }
    #pragma unroll
    for (int m = 0; m < 4; m++) {
        float2 w = tw2[m * 256 + tid];
        a0 += mk[m] * w.x;
        a1 += mk[m] * w.y;
    }
    float2 pe = pe2[(s + 1) * 256 + tid];
    float2 e1v = ((const float2*)(S + OFF_E1))[((size_t)b * 98 + (s + 1)) * 256 + tid];
    float2 o;
    o.x = a0 + pe.x + e1v.x;
    o.y = a1 + pe.y + e1v.y;
    ((float2*)(S + OFF_XC))[((size_t)b * 96 + s) * 256 + tid] = o;
}

// ---------------- kernel 3: mamba per (g, b, patch), MFMA -------------------
// Fragment convention (identical bijection used for packing A and B =>
// result invariant to the HW's internal k-slot permutation):
//   A: lane = row + 16*q holds A[row][ks*32 + q*8 + i]
//   B: lane = col + 16*q holds B[ks*32 + q*8 + i][col]
//   D (HW-verified): lane holds D[(lane>>4)*4 + reg][lane&15]
__global__ __launch_bounds__(256) void k_mamba(float* S,
                                               const float* __restrict__ conv1_b,
                                               const float* __restrict__ dt_b,
                                               const float* __restrict__ Dp) {
    int p = blockIdx.x, b = blockIdx.y, g = blockIdx.z;
    int tid = threadIdx.x;
    int l = tid & 63, w = tid >> 6;
    int lt = l & 15, lq = l >> 4;

    __shared__ __align__(16) short uplane[8192];   // x_hi[0..2047] x_lo[2048..4095]; then xq_hi[0..4095]; y_hi[4096..8191]
    __shared__ float xz[512 * 17];                 // [n][t]: n<256 a0, n>=256 z
    __shared__ __align__(16) float dtraw[16 * 12];
    __shared__ float Bm[16 * 17], Cm[16 * 17];

    // ---- A: load x tile, split hi/lo bf16 into swizzled planes ----
    {
        const float* xg = S + OFF_XC + ((size_t)b * 96 + p * 16) * 512 + g * 128;
        #pragma unroll
        for (int it = 0; it < 8; it++) {
            int i = it * 256 + tid;
            int t = i >> 7, j = i & 127;
            float v = xg[t * 512 + j];
            short hi = f2bf(v);
            short lo = f2bf(v - bf2f_s(hi));
            int bo = t * 256 + ((j * 2) ^ ((t & 7) << 4));
            uplane[bo >> 1] = hi;
            uplane[2048 + (bo >> 1)] = lo;
        }
    }
    __syncthreads();

    // ---- B: in-proj via MFMA (a_hi*b_hi + a_lo*b_hi + a_hi*b_lo) ----
    {
        short8 ah[4], al[4];
        #pragma unroll
        for (int ks = 0; ks < 4; ks++) {
            int c = (ks * 32 + lq * 8) * 2;
            int bo = lt * 256 + (c ^ ((lt & 7) << 4));
            ah[ks] = *(const short8*)((const char*)uplane + bo);
            al[ks] = *(const short8*)((const char*)uplane + 4096 + bo);
        }
        const short8* WF = (const short8*)(const void*)(S + OFF_WIN);
        #pragma unroll
        for (int ntl = 0; ntl < 8; ntl++) {
            int nt = w * 8 + ntl;
            float4v acc = {0.f, 0.f, 0.f, 0.f};
            #pragma unroll
            for (int ks = 0; ks < 4; ks++) {
                int fb = (((g * 32 + nt) * 4 + ks) * 2) * 64 + l;
                short8 bh = WF[fb];
                short8 bl = WF[fb + 64];
                acc = __builtin_amdgcn_mfma_f32_16x16x32_bf16(ah[ks], bh, acc, 0, 0, 0);
                acc = __builtin_amdgcn_mfma_f32_16x16x32_bf16(al[ks], bh, acc, 0, 0, 0);
                acc = __builtin_amdgcn_mfma_f32_16x16x32_bf16(ah[ks], bl, acc, 0, 0, 0);
            }
            int n = nt * 16 + lt;
            int t0 = lq * 4;
            #pragma unroll
            for (int r = 0; r < 4; r++) xz[n * 17 + t0 + r] = acc[r];
        }
    }
    __syncthreads();

    // ---- C: depthwise conv(4) + silu (regs), publish xq_hi plane ----
    float xq[16];
    {
        int e = tid, ge = g * 256 + e;
        float ar[16];
        #pragma unroll
        for (int t = 0; t < 16; t++) ar[t] = xz[e * 17 + t];
        float w0 = S[OFF_CW1T + 0 * 1024 + ge];
        float w1 = S[OFF_CW1T + 1 * 1024 + ge];
        float w2 = S[OFF_CW1T + 2 * 1024 + ge];
        float w3 = S[OFF_CW1T + 3 * 1024 + ge];
        float bb = conv1_b[ge];
        #pragma unroll
        for (int t = 0; t < 16; t++) {
            float sa = bb + w3 * ar[t];
            if (t >= 1) sa += w2 * ar[t - 1];
            if (t >= 2) sa += w1 * ar[t - 2];
            if (t >= 3) sa += w0 * ar[t - 3];
            xq[t] = sa * (1.f / (1.f + __expf(-sa)));
        }
        #pragma unroll
        for (int t = 0; t < 16; t++) {
            int bo = t * 512 + ((e * 2) ^ ((t & 7) << 4));
            uplane[bo >> 1] = f2bf(xq[t]);
        }
    }
    __syncthreads();

    // ---- D: x-proj via MFMA (hi only), waves 0..2 ----
    if (w < 3) {
        const short8* WXF = (const short8*)(const void*)(S + OFF_WXP);
        float4v acc = {0.f, 0.f, 0.f, 0.f};
        #pragma unroll
        for (int ks = 0; ks < 8; ks++) {
            int c = (ks * 32 + lq * 8) * 2;
            int bo = lt * 512 + (c ^ ((lt & 7) << 4));
            short8 a = *(const short8*)((const char*)uplane + bo);
            short8 bfr = WXF[((g * 3 + w) * 8 + ks) * 64 + l];
            acc = __builtin_amdgcn_mfma_f32_16x16x32_bf16(a, bfr, acc, 0, 0, 0);
        }
        int r = w * 16 + lt;
        if (r < 40) {
            int t0 = lq * 4;
            #pragma unroll
            for (int rr = 0; rr < 4; rr++) {
                float v = acc[rr];
                int t = t0 + rr;
                if (r < 8) dtraw[t * 12 + r] = v;
                else if (r < 24) Bm[t * 17 + (r - 8)] = v;
                else Cm[t * 17 + (r - 24)] = v;
            }
        }
    }
    __syncthreads();

    // ---- E+F: dt + selective scan (regs), publish y_hi plane ----
    {
        int e = tid, ge = g * 256 + e;
        float Av[16];
        #pragma unroll
        for (int n = 0; n < 16; n++) Av[n] = S[OFF_A2T + (g * 16 + n) * 256 + e];
        float dtw[8];
        #pragma unroll
        for (int r = 0; r < 8; r++) dtw[r] = S[OFF_DTWT + r * 1024 + ge];
        float dtbv = dt_b[ge];
        float Dv = Dp[ge];
        float h[16];
        #pragma unroll
        for (int n = 0; n < 16; n++) h[n] = 0.f;
        for (int t = 0; t < 16; t++) {
            const float4* q = (const float4*)&dtraw[t * 12];
            float4 q0 = q[0], q1 = q[1];
            float sa = dtbv + q0.x * dtw[0] + q0.y * dtw[1] + q0.z * dtw[2] + q0.w * dtw[3]
                            + q1.x * dtw[4] + q1.y * dtw[5] + q1.z * dtw[6] + q1.w * dtw[7];
            float dtv = (sa > 20.f) ? sa : log1pf(__expf(sa));
            float xv = xq[t];
            float dx = dtv * xv;
            float y = 0.f;
            #pragma unroll
            for (int n = 0; n < 16; n++) {
                h[n] = __expf(dtv * Av[n]) * h[n] + dx * Bm[t * 17 + n];
                y += h[n] * Cm[t * 17 + n];
            }
            y += Dv * xv;
            float zv = xz[(256 + e) * 17 + t];
            y *= zv * (1.f / (1.f + __expf(-zv)));
            int bo = t * 512 + ((e * 2) ^ ((t & 7) << 4));
            uplane[4096 + (bo >> 1)] = f2bf(y);
        }
    }
    __syncthreads();

    // ---- G: out-proj via MFMA (hi only), 2 n-tiles per wave ----
    {
        const short8* WOF = (const short8*)(const void*)(S + OFF_WOUT);
        #pragma unroll
        for (int ntl = 0; ntl < 2; ntl++) {
            int nt = w * 2 + ntl;
            float4v acc = {0.f, 0.f, 0.f, 0.f};
            #pragma unroll
            for (int ks = 0; ks < 8; ks++) {
                int c = (ks * 32 + lq * 8) * 2;
                int bo = 8192 + lt * 512 + (c ^ ((lt & 7) << 4));
                short8 a = *(const short8*)((const char*)uplane + bo);
                short8 bfr = WOF[((g * 8 + nt) * 8 + ks) * 64 + l];
                acc = __builtin_amdgcn_mfma_f32_16x16x32_bf16(a, bfr, acc, 0, 0, 0);
            }
            int j = nt * 16 + lt;
            int t0 = lq * 4;
            float* XM = S + OFF_XM + ((size_t)b * 96 + p * 16 + t0) * 512 + g * 128 + j;
            #pragma unroll
            for (int rr = 0; rr < 4; rr++) XM[rr * 512] = acc[rr];
        }
    }
}

// ---------------- kernel 4: final projection + de-normalize -----------------
__global__ __launch_bounds__(128) void k_out(float* S, float* __restrict__ out) {
    int s = blockIdx.x, b = blockIdx.y;
    int tid = threadIdx.x;
    int c = tid & 31, part = tid >> 5;
    __shared__ float red[4][32];
    const float* xr = S + OFF_XM + ((size_t)b * 96 + s) * 512;
    const float* owT = S + OFF_OWT;
    float p = 0.f;
    for (int d = part * 128; d < part * 128 + 128; d++) p += xr[d] * owT[d * 32 + c];
    red[part][c] = p;
    __syncthreads();
    if (tid < 32) {
        float Sm = red[0][tid] + red[1][tid] + red[2][tid] + red[3][tid];
        out[((size_t)b * 96 + s) * 32 + tid] = Sm * S[OFF_STD + b * 32 + tid] + S[OFF_MEAN + b * 32 + tid];
    }
}

extern "C" void kernel_launch(void* const* d_in, const int* in_sizes, int n_in,
                              void* d_out, int out_size, void* d_ws, size_t ws_size,
                              hipStream_t stream) {
    (void)in_sizes; (void)n_in; (void)out_size;
    const float* x_enc   = (const float*)d_in[0];
    const float* mark    = (const float*)d_in[1];
    const float* conv_w  = (const float*)d_in[4];
    const float* temp_w  = (const float*)d_in[5];
    const float* het_w   = (const float*)d_in[6];
    const float* het_b   = (const float*)d_in[7];
    const float* in_proj = (const float*)d_in[8];
    const float* conv1_w = (const float*)d_in[9];
    const float* conv1_b = (const float*)d_in[10];
    const float* xp_w    = (const float*)d_in[11];
    const float* dt_w    = (const float*)d_in[12];
    const float* dt_b    = (const float*)d_in[13];
    const float* A_log   = (const float*)d_in[14];
    const float* D_param = (const float*)d_in[15];
    const float* outp_w  = (const float*)d_in[16];
    const float* ow      = (const float*)d_in[17];
    float* out = (float*)d_out;

    float* S = (float*)d_ws;
    if (ws_size < (size_t)WS_FLOATS * sizeof(float)) {
        void* p = nullptr;
        hipGetSymbolAddress(&p, HIP_SYMBOL(g_fb));
        S = (float*)p;
    }

    k_prep<<<dim3(160), dim3(256), 0, stream>>>(S, x_enc, in_proj, outp_w, xp_w, het_w, ow,
                                                conv_w, temp_w, A_log, conv1_w, dt_w);
    k_e1<<<dim3(98, 32), dim3(256), 0, stream>>>(S, x_enc, mark, het_b);
    k_xc<<<dim3(96, 32), dim3(256), 0, stream>>>(S, x_enc, mark);
    k_mamba<<<dim3(6, 32, 4), dim3(256), 0, stream>>>(S, conv1_b, dt_b, D_param);
    k_out<<<dim3(96, 32), dim3(128), 0, stream>>>(S, out);
}

// Round 5
// 136.797 us; speedup vs baseline: 2.1837x; 1.3139x over previous
//
#include <hip/hip_runtime.h>
#include <hip/hip_bf16.h>
#include <math.h>

#define LN10000 9.210340371976184f

typedef __attribute__((ext_vector_type(8))) short short8;
typedef __attribute__((ext_vector_type(4))) float float4v;

// ---- scratch layout (float offsets into workspace) ----
#define OFF_MEAN   0
#define OFF_ISTD   1024
#define OFF_STD    2048
#define OFF_E1     3072              // 32*98*512
#define OFF_SCALE  1608704           // 32*98*32
#define OFF_XC     1709056           // 32*96*512
#define OFF_XM     3281920           // 32*96*512
#define OFF_WIN    4854784           // in-proj frags: 4g*32nt*4ks*2hl*512 ushort = 262144 fl
#define OFF_WXP    5116928           // x-proj frags: 4g*3nt*8ks*512 ushort = 24576 fl
#define OFF_WOUT   5141504           // out-proj frags: 4g*8nt*8ks*512 ushort = 65536 fl
#define OFF_HETT   5207040           // 512*32 [d][c]
#define OFF_OWT    5223424           // 512*32 [d][c]
#define OFF_CWT    5239808           // 96*512 [c*3+k][d]
#define OFF_TWT    5288960           // 4*512  [m][d]
#define OFF_PE     5291008           // 98*512 [ii][d]
#define OFF_A2T    5341184           // 4*16*256 [g][n][e] = -exp(A_log)
#define OFF_CW1T   5357568           // 4*1024 [k][g*256+e]
#define OFF_DTWT   5361664           // 8*1024 [r][g*256+e]
#define WS_FLOATS  5369856

__device__ float g_fb[WS_FLOATS];    // fallback if ws_size too small

__device__ inline short f2bf(float x) {
    __hip_bfloat16 h = __float2bfloat16(x);
    return *reinterpret_cast<short*>(&h);
}
__device__ inline float bf2f_s(short s) {
    __hip_bfloat16 h = *reinterpret_cast<__hip_bfloat16*>(&s);
    return __bfloat162float(h);
}

// ---------------- kernel 0: stats (blocks 0..31) + weight prep/pack ---------
__global__ __launch_bounds__(256) void k_prep(float* S,
                                              const float* __restrict__ x,
                                              const float* __restrict__ in_w,
                                              const float* __restrict__ outp_w,
                                              const float* __restrict__ xp_w,
                                              const float* __restrict__ het_w,
                                              const float* __restrict__ ow,
                                              const float* __restrict__ conv_w,
                                              const float* __restrict__ temp_w,
                                              const float* __restrict__ A_log,
                                              const float* __restrict__ conv1_w,
                                              const float* __restrict__ dt_w) {
    __shared__ float shs[8][32], shq[8][32];
    if (blockIdx.x < 32) {
        int b = blockIdx.x;
        int c = threadIdx.x & 31, r = threadIdx.x >> 5;
        const float* xb = x + (size_t)b * 1024 * 32;
        float s = 0.f, s2 = 0.f;
        for (int l = r; l < 1024; l += 8) {
            float v = xb[l * 32 + c];
            s += v; s2 += v * v;
        }
        shs[r][c] = s; shq[r][c] = s2;
        __syncthreads();
        if (threadIdx.x < 32) {
            float Sm = 0.f, Q = 0.f;
            for (int i = 0; i < 8; i++) { Sm += shs[i][threadIdx.x]; Q += shq[i][threadIdx.x]; }
            float m = Sm * (1.f / 1024.f);
            float var = Q * (1.f / 1024.f) - m * m;
            float sd = sqrtf(var + 1e-5f);
            S[OFF_MEAN + b * 32 + threadIdx.x] = m;
            S[OFF_STD  + b * 32 + threadIdx.x] = sd;
            S[OFF_ISTD + b * 32 + threadIdx.x] = 1.f / sd;
        }
        return;
    }
    const int base = (blockIdx.x - 32) * 256 + threadIdx.x;
    const int pstride = (gridDim.x - 32) << 8;

    // in-proj pack, READ-ordered (coalesced source): i over in_w elements
    {
        short* WIN = (short*)(void*)(S + OFF_WIN);
        for (int i = base; i < 4 * 512 * 128; i += pstride) {
            int g = i >> 16;
            int n = (i >> 7) & 511;
            int k = i & 127;
            float v = in_w[i];
            short hi = f2bf(v);
            short lo = f2bf(v - bf2f_s(hi));
            int nt = n >> 4, ks = k >> 5, i3 = k & 7;
            int lane = (n & 15) + 16 * ((k >> 3) & 3);
            int du = ((((g * 32 + nt) * 4 + ks) * 2) * 64 + lane) * 8 + i3;
            WIN[du] = hi;
            WIN[du + 512] = lo;
        }
    }
    // x-proj pack, dest-ordered (small, needs zero-fill rows 40..47)
    {
        short* WXP = (short*)(void*)(S + OFF_WXP);
        for (int u = base; u < 4 * 3 * 8 * 512; u += pstride) {
            int i = u & 7;
            int lane = (u >> 3) & 63;
            int ks = (u >> 9) & 7;
            int rest = u >> 12;
            int g = rest / 3, nt = rest % 3;
            int r = nt * 16 + (lane & 15);
            int e = ks * 32 + (lane >> 4) * 8 + i;
            float v = (r < 40) ? xp_w[(g * 40 + r) * 256 + e] : 0.f;
            WXP[u] = f2bf(v);
        }
    }
    // out-proj pack, READ-ordered
    {
        short* WOUT = (short*)(void*)(S + OFF_WOUT);
        for (int i = base; i < 4 * 128 * 256; i += pstride) {
            int g = i >> 15;
            int j = (i >> 8) & 127;
            int e = i & 255;
            int nt = j >> 4, ks = e >> 5, i3 = e & 7;
            int lane = (j & 15) + 16 * ((e >> 3) & 3);
            int du = (((g * 8 + nt) * 8 + ks) * 64 + lane) * 8 + i3;
            WOUT[du] = f2bf(outp_w[i]);
        }
    }
    for (int i = base; i < 32 * 512; i += pstride) {
        int c = i / 512, d = i % 512;
        S[OFF_HETT + d * 32 + c] = het_w[i];
        S[OFF_OWT  + d * 32 + c] = ow[i];
    }
    for (int i = base; i < 512 * 96; i += pstride) {
        int d = i / 96, r = i % 96;
        S[OFF_CWT + r * 512 + d] = conv_w[i];
    }
    for (int i = base; i < 512 * 4; i += pstride) {
        int d = i / 4, m = i % 4;
        S[OFF_TWT + m * 512 + d] = temp_w[i];
    }
    for (int i = base; i < 98 * 256; i += pstride) {
        int ii = i >> 8, q = i & 255;
        int l = (ii == 97) ? 0 : (927 + ii);
        float div = __expf((float)(2 * q) * (-LN10000 / 512.f));
        float sv, cv;
        sincosf((float)l * div, &sv, &cv);
        S[OFF_PE + ii * 512 + 2 * q]     = sv;
        S[OFF_PE + ii * 512 + 2 * q + 1] = cv;
    }
    for (int i = base; i < 4 * 16 * 256; i += pstride) {
        int g = i >> 12, n = (i >> 8) & 15, e = i & 255;
        S[OFF_A2T + i] = -__expf(A_log[(g * 256 + e) * 16 + n]);
    }
    for (int i = base; i < 4 * 1024; i += pstride) {
        int k = i >> 10, ge = i & 1023;
        S[OFF_CW1T + i] = conv1_w[ge * 4 + k];
    }
    for (int i = base; i < 8 * 1024; i += pstride) {
        int r = i >> 10, ge = i & 1023;
        S[OFF_DTWT + i] = dt_w[ge * 8 + r];
    }
}

// ---------------- kernel 1: e1 + scale, NP1 positions per block -------------
#define NP1 7
__global__ __launch_bounds__(256) void k_e1(float* S,
                                            const float* __restrict__ x_enc,
                                            const float* __restrict__ mark,
                                            const float* __restrict__ het_b) {
    int bx = blockIdx.x, b = blockIdx.y;
    int tid = threadIdx.x;
    __shared__ __align__(16) float xsf[NP1][96];
    __shared__ float mk[NP1][4];
    __shared__ __align__(16) float e1s[NP1][512];
    __shared__ float red3[8][NP1][32];
    for (int i = tid; i < NP1 * 96; i += 256) {
        int ip = i / 96, r = i - ip * 96;
        int k = r >> 5, c = r & 31;
        int ii = bx * NP1 + ip;
        int l = (ii == 97) ? 0 : (927 + ii);
        int la = l - 1 + k;
        la = (la < 0) ? la + 1024 : ((la >= 1024) ? la - 1024 : la);
        xsf[ip][c * 3 + k] = (x_enc[((size_t)b * 1024 + la) * 32 + c] - S[OFF_MEAN + b * 32 + c]) * S[OFF_ISTD + b * 32 + c];
    }
    if (tid < NP1 * 4) {
        int ip = tid >> 2, m = tid & 3;
        int ii = bx * NP1 + ip;
        int l = (ii == 97) ? 0 : (927 + ii);
        mk[ip][m] = mark[((size_t)b * 1024 + l) * 4 + m];
    }
    __syncthreads();

    const float2* cw2 = (const float2*)(S + OFF_CWT);
    const float2* tw2 = (const float2*)(S + OFF_TWT);
    const float2* pe2 = (const float2*)(S + OFF_PE);
    float acc0[NP1], acc1[NP1];
    #pragma unroll
    for (int ip = 0; ip < NP1; ip++) { acc0[ip] = 0.f; acc1[ip] = 0.f; }
    #pragma unroll 2
    for (int j4 = 0; j4 < 24; j4++) {
        float2 w0 = cw2[(j4 * 4 + 0) * 256 + tid];
        float2 w1 = cw2[(j4 * 4 + 1) * 256 + tid];
        float2 w2 = cw2[(j4 * 4 + 2) * 256 + tid];
        float2 w3 = cw2[(j4 * 4 + 3) * 256 + tid];
        #pragma unroll
        for (int ip = 0; ip < NP1; ip++) {
            float4 xv = ((const float4*)&xsf[ip][0])[j4];
            acc0[ip] += xv.x * w0.x + xv.y * w1.x + xv.z * w2.x + xv.w * w3.x;
            acc1[ip] += xv.x * w0.y + xv.y * w1.y + xv.z * w2.y + xv.w * w3.y;
        }
    }
    #pragma unroll
    for (int m = 0; m < 4; m++) {
        float2 w = tw2[m * 256 + tid];
        #pragma unroll
        for (int ip = 0; ip < NP1; ip++) {
            acc0[ip] += mk[ip][m] * w.x;
            acc1[ip] += mk[ip][m] * w.y;
        }
    }
    #pragma unroll
    for (int ip = 0; ip < NP1; ip++) {
        int ii = bx * NP1 + ip;
        float2 pe = pe2[ii * 256 + tid];
        float t0 = acc0[ip] + pe.x, t1 = acc1[ip] + pe.y;
        e1s[ip][2 * tid] = t0; e1s[ip][2 * tid + 1] = t1;
        float2 e1o; e1o.x = t0; e1o.y = t1;
        ((float2*)(S + OFF_E1))[((size_t)b * 98 + ii) * 256 + tid] = e1o;
    }
    __syncthreads();

    // scale partials: loop-transposed so weight is scalar (no runtime array idx)
    int c = tid & 31, part = tid >> 5;
    const float* hetT = S + OFF_HETT;
    float p[NP1];
    #pragma unroll
    for (int ip = 0; ip < NP1; ip++) p[ip] = 0.f;
    #pragma unroll 8
    for (int d = 0; d < 64; d++) {
        float w = hetT[(part * 64 + d) * 32 + c];
        #pragma unroll
        for (int ip = 0; ip < NP1; ip++) p[ip] += e1s[ip][part * 64 + d] * w;
    }
    #pragma unroll
    for (int ip = 0; ip < NP1; ip++) red3[part][ip][c] = p[ip];
    __syncthreads();
    int ipp = tid >> 5;
    if (ipp < NP1) {
        float Sm = het_b[c];
        #pragma unroll
        for (int i = 0; i < 8; i++) Sm += red3[i][ipp][c];
        S[OFF_SCALE + ((size_t)b * 98 + bx * NP1 + ipp) * 32 + c] = __expf(Sm);
    }
}

// ---------------- kernel 2: xc = e1 + e2, NP2 positions per block -----------
#define NP2 8
__global__ __launch_bounds__(256) void k_xc(float* S,
                                            const float* __restrict__ x_enc,
                                            const float* __restrict__ mark) {
    int bx = blockIdx.x, b = blockIdx.y;
    int tid = threadIdx.x;
    __shared__ __align__(16) float xsf[NP2][96];
    __shared__ float mk[NP2][4];
    for (int i = tid; i < NP2 * 96; i += 256) {
        int ip = i / 96, r = i - ip * 96;
        int k = r >> 5, c = r & 31;
        int s = bx * NP2 + ip;
        int l = 928 + s;
        int la = l - 1 + k;
        if (la >= 1024) la -= 1024;
        int idx = (la == 0) ? 97 : (la - 927);
        float xn = (x_enc[((size_t)b * 1024 + la) * 32 + c] - S[OFF_MEAN + b * 32 + c]) * S[OFF_ISTD + b * 32 + c];
        xsf[ip][c * 3 + k] = xn * S[OFF_SCALE + ((size_t)b * 98 + idx) * 32 + c];
    }
    if (tid < NP2 * 4) {
        int ip = tid >> 2, m = tid & 3;
        int l = 928 + bx * NP2 + ip;
        mk[ip][m] = mark[((size_t)b * 1024 + l) * 4 + m];
    }
    __syncthreads();

    const float2* cw2 = (const float2*)(S + OFF_CWT);
    const float2* tw2 = (const float2*)(S + OFF_TWT);
    const float2* pe2 = (const float2*)(S + OFF_PE);
    float acc0[NP2], acc1[NP2];
    #pragma unroll
    for (int ip = 0; ip < NP2; ip++) { acc0[ip] = 0.f; acc1[ip] = 0.f; }
    #pragma unroll 2
    for (int j4 = 0; j4 < 24; j4++) {
        float2 w0 = cw2[(j4 * 4 + 0) * 256 + tid];
        float2 w1 = cw2[(j4 * 4 + 1) * 256 + tid];
        float2 w2 = cw2[(j4 * 4 + 2) * 256 + tid];
        float2 w3 = cw2[(j4 * 4 + 3) * 256 + tid];
        #pragma unroll
        for (int ip = 0; ip < NP2; ip++) {
            float4 xv = ((const float4*)&xsf[ip][0])[j4];
            acc0[ip] += xv.x * w0.x + xv.y * w1.x + xv.z * w2.x + xv.w * w3.x;
            acc1[ip] += xv.x * w0.y + xv.y * w1.y + xv.z * w2.y + xv.w * w3.y;
        }
    }
    #pragma unroll
    for (int m = 0; m < 4; m++) {
        float2 w = tw2[m * 256 + tid];
        #pragma unroll
        for (int ip = 0; ip < NP2; ip++) {
            acc0[ip] += mk[ip][m] * w.x;
            acc1[ip] += mk[ip][m] * w.y;
        }
    }
    #pragma unroll
    for (int ip = 0; ip < NP2; ip++) {
        int s = bx * NP2 + ip;
        float2 pe = pe2[(s + 1) * 256 + tid];
        float2 e1v = ((const float2*)(S + OFF_E1))[((size_t)b * 98 + (s + 1)) * 256 + tid];
        float2 o;
        o.x = acc0[ip] + pe.x + e1v.x;
        o.y = acc1[ip] + pe.y + e1v.y;
        ((float2*)(S + OFF_XC))[((size_t)b * 96 + s) * 256 + tid] = o;
    }
}

// ---------------- kernel 3: mamba per (g, b, patch), MFMA -------------------
// Fragment convention (identical bijection used for packing A and B =>
// result invariant to the HW's internal k-slot permutation):
//   A: lane = row + 16*q holds A[row][ks*32 + q*8 + i]
//   B: lane = col + 16*q holds B[ks*32 + q*8 + i][col]
//   D (HW-verified): lane holds D[(lane>>4)*4 + reg][lane&15]
__global__ __launch_bounds__(256) void k_mamba(float* S,
                                               const float* __restrict__ conv1_b,
                                               const float* __restrict__ dt_b,
                                               const float* __restrict__ Dp) {
    int p = blockIdx.x, b = blockIdx.y, g = blockIdx.z;
    int tid = threadIdx.x;
    int l = tid & 63, w = tid >> 6;
    int lt = l & 15, lq = l >> 4;

    __shared__ __align__(16) short uplane[8192];   // x_hi/x_lo; then xq_hi; y_hi
    __shared__ float xz[512 * 17];                 // [n][t]: n<256 a0, n>=256 z
    __shared__ __align__(16) float dtraw[16 * 12];
    __shared__ float Bm[16 * 17], Cm[16 * 17];

    // ---- A: load x tile, split hi/lo bf16 into swizzled planes ----
    {
        const float* xg = S + OFF_XC + ((size_t)b * 96 + p * 16) * 512 + g * 128;
        #pragma unroll
        for (int it = 0; it < 8; it++) {
            int i = it * 256 + tid;
            int t = i >> 7, j = i & 127;
            float v = xg[t * 512 + j];
            short hi = f2bf(v);
            short lo = f2bf(v - bf2f_s(hi));
            int bo = t * 256 + ((j * 2) ^ ((t & 7) << 4));
            uplane[bo >> 1] = hi;
            uplane[2048 + (bo >> 1)] = lo;
        }
    }
    __syncthreads();

    // ---- B: in-proj via MFMA (a_hi*b_hi + a_lo*b_hi + a_hi*b_lo) ----
    {
        short8 ah[4], al[4];
        #pragma unroll
        for (int ks = 0; ks < 4; ks++) {
            int c = (ks * 32 + lq * 8) * 2;
            int bo = lt * 256 + (c ^ ((lt & 7) << 4));
            ah[ks] = *(const short8*)((const char*)uplane + bo);
            al[ks] = *(const short8*)((const char*)uplane + 4096 + bo);
        }
        const short8* WF = (const short8*)(const void*)(S + OFF_WIN);
        #pragma unroll
        for (int ntl = 0; ntl < 8; ntl++) {
            int nt = w * 8 + ntl;
            float4v acc = {0.f, 0.f, 0.f, 0.f};
            #pragma unroll
            for (int ks = 0; ks < 4; ks++) {
                int fb = (((g * 32 + nt) * 4 + ks) * 2) * 64 + l;
                short8 bh = WF[fb];
                short8 bl = WF[fb + 64];
                acc = __builtin_amdgcn_mfma_f32_16x16x32_bf16(ah[ks], bh, acc, 0, 0, 0);
                acc = __builtin_amdgcn_mfma_f32_16x16x32_bf16(al[ks], bh, acc, 0, 0, 0);
                acc = __builtin_amdgcn_mfma_f32_16x16x32_bf16(ah[ks], bl, acc, 0, 0, 0);
            }
            int n = nt * 16 + lt;
            int t0 = lq * 4;
            #pragma unroll
            for (int r = 0; r < 4; r++) xz[n * 17 + t0 + r] = acc[r];
        }
    }
    __syncthreads();

    // ---- C: depthwise conv(4) + silu (regs), publish xq_hi plane ----
    float xq[16];
    {
        int e = tid, ge = g * 256 + e;
        float ar[16];
        #pragma unroll
        for (int t = 0; t < 16; t++) ar[t] = xz[e * 17 + t];
        float w0 = S[OFF_CW1T + 0 * 1024 + ge];
        float w1 = S[OFF_CW1T + 1 * 1024 + ge];
        float w2 = S[OFF_CW1T + 2 * 1024 + ge];
        float w3 = S[OFF_CW1T + 3 * 1024 + ge];
        float bb = conv1_b[ge];
        #pragma unroll
        for (int t = 0; t < 16; t++) {
            float sa = bb + w3 * ar[t];
            if (t >= 1) sa += w2 * ar[t - 1];
            if (t >= 2) sa += w1 * ar[t - 2];
            if (t >= 3) sa += w0 * ar[t - 3];
            xq[t] = sa * (1.f / (1.f + __expf(-sa)));
        }
        #pragma unroll
        for (int t = 0; t < 16; t++) {
            int bo = t * 512 + ((e * 2) ^ ((t & 7) << 4));
            uplane[bo >> 1] = f2bf(xq[t]);
        }
    }
    __syncthreads();

    // ---- D: x-proj via MFMA (hi only), waves 0..2 ----
    if (w < 3) {
        const short8* WXF = (const short8*)(const void*)(S + OFF_WXP);
        float4v acc = {0.f, 0.f, 0.f, 0.f};
        #pragma unroll
        for (int ks = 0; ks < 8; ks++) {
            int c = (ks * 32 + lq * 8) * 2;
            int bo = lt * 512 + (c ^ ((lt & 7) << 4));
            short8 a = *(const short8*)((const char*)uplane + bo);
            short8 bfr = WXF[((g * 3 + w) * 8 + ks) * 64 + l];
            acc = __builtin_amdgcn_mfma_f32_16x16x32_bf16(a, bfr, acc, 0, 0, 0);
        }
        int r = w * 16 + lt;
        if (r < 40) {
            int t0 = lq * 4;
            #pragma unroll
            for (int rr = 0; rr < 4; rr++) {
                float v = acc[rr];
                int t = t0 + rr;
                if (r < 8) dtraw[t * 12 + r] = v;
                else if (r < 24) Bm[t * 17 + (r - 8)] = v;
                else Cm[t * 17 + (r - 24)] = v;
            }
        }
    }
    __syncthreads();

    // ---- E+F: dt + selective scan (regs), publish y_hi plane ----
    {
        int e = tid, ge = g * 256 + e;
        float Av[16];
        #pragma unroll
        for (int n = 0; n < 16; n++) Av[n] = S[OFF_A2T + (g * 16 + n) * 256 + e];
        float dtw[8];
        #pragma unroll
        for (int r = 0; r < 8; r++) dtw[r] = S[OFF_DTWT + r * 1024 + ge];
        float dtbv = dt_b[ge];
        float Dv = Dp[ge];
        float h[16];
        #pragma unroll
        for (int n = 0; n < 16; n++) h[n] = 0.f;
        for (int t = 0; t < 16; t++) {
            const float4* q = (const float4*)&dtraw[t * 12];
            float4 q0 = q[0], q1 = q[1];
            float sa = dtbv + q0.x * dtw[0] + q0.y * dtw[1] + q0.z * dtw[2] + q0.w * dtw[3]
                            + q1.x * dtw[4] + q1.y * dtw[5] + q1.z * dtw[6] + q1.w * dtw[7];
            float dtv = (sa > 20.f) ? sa : log1pf(__expf(sa));
            float xv = xq[t];
            float dx = dtv * xv;
            float y = 0.f;
            #pragma unroll
            for (int n = 0; n < 16; n++) {
                h[n] = __expf(dtv * Av[n]) * h[n] + dx * Bm[t * 17 + n];
                y += h[n] * Cm[t * 17 + n];
            }
            y += Dv * xv;
            float zv = xz[(256 + e) * 17 + t];
            y *= zv * (1.f / (1.f + __expf(-zv)));
            int bo = t * 512 + ((e * 2) ^ ((t & 7) << 4));
            uplane[4096 + (bo >> 1)] = f2bf(y);
        }
    }
    __syncthreads();

    // ---- G: out-proj via MFMA (hi only), 2 n-tiles per wave ----
    {
        const short8* WOF = (const short8*)(const void*)(S + OFF_WOUT);
        #pragma unroll
        for (int ntl = 0; ntl < 2; ntl++) {
            int nt = w * 2 + ntl;
            float4v acc = {0.f, 0.f, 0.f, 0.f};
            #pragma unroll
            for (int ks = 0; ks < 8; ks++) {
                int c = (ks * 32 + lq * 8) * 2;
                int bo = 8192 + lt * 512 + (c ^ ((lt & 7) << 4));
                short8 a = *(const short8*)((const char*)uplane + bo);
                short8 bfr = WOF[((g * 8 + nt) * 8 + ks) * 64 + l];
                acc = __builtin_amdgcn_mfma_f32_16x16x32_bf16(a, bfr, acc, 0, 0, 0);
            }
            int j = nt * 16 + lt;
            int t0 = lq * 4;
            float* XM = S + OFF_XM + ((size_t)b * 96 + p * 16 + t0) * 512 + g * 128 + j;
            #pragma unroll
            for (int rr = 0; rr < 4; rr++) XM[rr * 512] = acc[rr];
        }
    }
}

// ---------------- kernel 4: final projection + de-normalize, 8 pos/block ----
#define NPO 8
__global__ __launch_bounds__(256) void k_out(float* S, float* __restrict__ out) {
    int bx = blockIdx.x, b = blockIdx.y;   // grid (12, 32)
    int tid = threadIdx.x;
    int c = tid & 31, part = tid >> 5;     // 8 parts x 64 d
    __shared__ __align__(16) float xls[NPO][512];
    __shared__ float red[8][NPO][32];
    for (int i = tid; i < NPO * 512; i += 256) {
        int ip = i >> 9, d = i & 511;
        xls[ip][d] = S[OFF_XM + ((size_t)b * 96 + bx * NPO + ip) * 512 + d];
    }
    __syncthreads();
    const float* owT = S + OFF_OWT;
    float acc[NPO];
    #pragma unroll
    for (int ip = 0; ip < NPO; ip++) acc[ip] = 0.f;
    #pragma unroll 8
    for (int d = 0; d < 64; d++) {
        float w = owT[(part * 64 + d) * 32 + c];
        #pragma unroll
        for (int ip = 0; ip < NPO; ip++) acc[ip] += xls[ip][part * 64 + d] * w;
    }
    #pragma unroll
    for (int ip = 0; ip < NPO; ip++) red[part][ip][c] = acc[ip];
    __syncthreads();
    int ipo = tid >> 5;
    float Sm = 0.f;
    #pragma unroll
    for (int i = 0; i < 8; i++) Sm += red[i][ipo][c];
    int s = bx * NPO + ipo;
    out[((size_t)b * 96 + s) * 32 + c] = Sm * S[OFF_STD + b * 32 + c] + S[OFF_MEAN + b * 32 + c];
}

extern "C" void kernel_launch(void* const* d_in, const int* in_sizes, int n_in,
                              void* d_out, int out_size, void* d_ws, size_t ws_size,
                              hipStream_t stream) {
    (void)in_sizes; (void)n_in; (void)out_size;
    const float* x_enc   = (const float*)d_in[0];
    const float* mark    = (const float*)d_in[1];
    const float* conv_w  = (const float*)d_in[4];
    const float* temp_w  = (const float*)d_in[5];
    const float* het_w   = (const float*)d_in[6];
    const float* het_b   = (const float*)d_in[7];
    const float* in_proj = (const float*)d_in[8];
    const float* conv1_w = (const float*)d_in[9];
    const float* conv1_b = (const float*)d_in[10];
    const float* xp_w    = (const float*)d_in[11];
    const float* dt_w    = (const float*)d_in[12];
    const float* dt_b    = (const float*)d_in[13];
    const float* A_log   = (const float*)d_in[14];
    const float* D_param = (const float*)d_in[15];
    const float* outp_w  = (const float*)d_in[16];
    const float* ow      = (const float*)d_in[17];
    float* out = (float*)d_out;

    float* S = (float*)d_ws;
    if (ws_size < (size_t)WS_FLOATS * sizeof(float)) {
        void* p = nullptr;
        hipGetSymbolAddress(&p, HIP_SYMBOL(g_fb));
        S = (float*)p;
    }

    k_prep<<<dim3(288), dim3(256), 0, stream>>>(S, x_enc, in_proj, outp_w, xp_w, het_w, ow,
                                                conv_w, temp_w, A_log, conv1_w, dt_w);
    k_e1<<<dim3(14, 32), dim3(256), 0, stream>>>(S, x_enc, mark, het_b);
    k_xc<<<dim3(12, 32), dim3(256), 0, stream>>>(S, x_enc, mark);
    k_mamba<<<dim3(6, 32, 4), dim3(256), 0, stream>>>(S, conv1_b, dt_b, D_param);
    k_out<<<dim3(12, 32), dim3(256), 0, stream>>>(S, out);
}

// Round 6
// 106.940 us; speedup vs baseline: 2.7934x; 1.2792x over previous
//
#include <hip/hip_runtime.h>
#include <hip/hip_bf16.h>
#include <math.h>

#define LN10000 9.210340371976184f

typedef __attribute__((ext_vector_type(8))) short short8;
typedef __attribute__((ext_vector_type(4))) float float4v;

// ---- scratch layout (float offsets into workspace) ----
#define OFF_E1     3072              // 32*98*512
#define OFF_SCALE  1608704           // 32*98*32
#define OFF_XC     1709056           // 32*96*512
#define OFF_XM     3281920           // 32*96*512
#define OFF_WIN    4854784           // in-proj frags: 4g*32nt*4ks*2hl*512 ushort = 262144 fl
#define OFF_WXP    5116928           // x-proj frags: 4g*3nt*8ks*512 ushort = 24576 fl
#define OFF_WOUT   5141504           // out-proj frags: 4g*8nt*8ks*512 ushort = 65536 fl
#define OFF_HETT   5207040           // 512*32 [d][c]
#define OFF_OWT    5223424           // 512*32 [d][c]
#define OFF_CWT    5239808           // 96*512 [c*3+k][d]
#define OFF_TWT    5288960           // 4*512  [m][d]
#define OFF_PE     5291008           // 98*512 [ii][d]
#define OFF_A2T    5341184           // 4*16*256 [g][n][e] = -exp(A_log)
#define OFF_CW1T   5357568           // 4*1024 [k][g*256+e]
#define OFF_DTWT   5361664           // 8*1024 [r][g*256+e]
#define OFF_SPART  5369856           // 32b*8bx*64 (s[32], q[32]) partial stats
#define WS_FLOATS  5386240

__device__ float g_fb[WS_FLOATS];    // fallback if ws_size too small

__device__ inline short f2bf(float x) {
    __hip_bfloat16 h = __float2bfloat16(x);
    return *reinterpret_cast<short*>(&h);
}
__device__ inline float bf2f_s(short s) {
    __hip_bfloat16 h = *reinterpret_cast<__hip_bfloat16*>(&s);
    return __bfloat162float(h);
}

// each consumer block reduces the 8 stats partials itself (16 L2 loads)
__device__ inline void stats_load(const float* S, int b, int tid,
                                  float* sm, float* si, float* sd) {
    if (tid < 32) {
        float s = 0.f, q = 0.f;
        #pragma unroll
        for (int i = 0; i < 8; i++) {
            s += S[OFF_SPART + ((b * 8 + i) << 6) + tid];
            q += S[OFF_SPART + ((b * 8 + i) << 6) + 32 + tid];
        }
        float m = s * (1.f / 1024.f);
        float var = q * (1.f / 1024.f) - m * m;
        float sdv = sqrtf(var + 1e-5f);
        sm[tid] = m;
        if (si) si[tid] = 1.f / sdv;
        if (sd) sd[tid] = sdv;
    }
}

// ---------------- kernel S: stats partials, grid (8, 32) --------------------
__global__ __launch_bounds__(256) void k_stats(float* S, const float* __restrict__ x) {
    int bx = blockIdx.x, b = blockIdx.y;
    int tid = threadIdx.x;
    int c4 = tid & 7, rl = tid >> 3;
    const float4* xb = (const float4*)(x + (size_t)b * 32768) + c4;
    float s0 = 0.f, s1 = 0.f, s2 = 0.f, s3 = 0.f;
    float q0 = 0.f, q1 = 0.f, q2 = 0.f, q3 = 0.f;
    #pragma unroll
    for (int i = 0; i < 4; i++) {
        int l = bx * 128 + rl + i * 32;
        float4 v = xb[l * 8];
        s0 += v.x; q0 += v.x * v.x;
        s1 += v.y; q1 += v.y * v.y;
        s2 += v.z; q2 += v.z * v.z;
        s3 += v.w; q3 += v.w * v.w;
    }
    __shared__ float rs[32][33], rq[32][33];
    rs[rl][c4 * 4 + 0] = s0; rq[rl][c4 * 4 + 0] = q0;
    rs[rl][c4 * 4 + 1] = s1; rq[rl][c4 * 4 + 1] = q1;
    rs[rl][c4 * 4 + 2] = s2; rq[rl][c4 * 4 + 2] = q2;
    rs[rl][c4 * 4 + 3] = s3; rq[rl][c4 * 4 + 3] = q3;
    __syncthreads();
    if (tid < 32) {
        float s = 0.f, q = 0.f;
        #pragma unroll
        for (int i = 0; i < 32; i++) { s += rs[i][tid]; q += rq[i][tid]; }
        S[OFF_SPART + ((b * 8 + bx) << 6) + tid] = s;
        S[OFF_SPART + ((b * 8 + bx) << 6) + 32 + tid] = q;
    }
}

// ---------------- kernel 0: weight prep/pack (grid 256) ---------------------
__global__ __launch_bounds__(256) void k_prep(float* S,
                                              const float* __restrict__ in_w,
                                              const float* __restrict__ outp_w,
                                              const float* __restrict__ xp_w,
                                              const float* __restrict__ het_w,
                                              const float* __restrict__ ow,
                                              const float* __restrict__ conv_w,
                                              const float* __restrict__ temp_w,
                                              const float* __restrict__ A_log,
                                              const float* __restrict__ conv1_w,
                                              const float* __restrict__ dt_w) {
    const int base = blockIdx.x * 256 + threadIdx.x;
    const int pstride = gridDim.x << 8;

    // in-proj pack: thread handles 8 consecutive k (one short8 per plane)
    {
        short8* WIN8 = (short8*)(void*)(S + OFF_WIN);
        for (int u = base; u < 4 * 512 * 16; u += pstride) {
            int g = u >> 13;
            int n = (u >> 4) & 511;
            int k8 = u & 15;
            const float4* src = (const float4*)(in_w + ((size_t)(g * 512 + n)) * 128 + k8 * 8);
            float arr[8];
            *(float4*)&arr[0] = src[0];
            *(float4*)&arr[4] = src[1];
            short8 h8, l8;
            #pragma unroll
            for (int j = 0; j < 8; j++) {
                short hi = f2bf(arr[j]);
                h8[j] = hi;
                l8[j] = f2bf(arr[j] - bf2f_s(hi));
            }
            int ks = k8 >> 2;
            int lane = (n & 15) + 16 * (k8 & 3);
            int du8 = (((g * 32 + (n >> 4)) * 4 + ks) * 2) * 64 + lane;
            WIN8[du8] = h8;
            WIN8[du8 + 64] = l8;
        }
    }
    // x-proj pack, dest-ordered (small, zero-fill rows 40..47)
    {
        short* WXP = (short*)(void*)(S + OFF_WXP);
        for (int u = base; u < 4 * 3 * 8 * 512; u += pstride) {
            int i = u & 7;
            int lane = (u >> 3) & 63;
            int ks = (u >> 9) & 7;
            int rest = u >> 12;
            int g = rest / 3, nt = rest % 3;
            int r = nt * 16 + (lane & 15);
            int e = ks * 32 + (lane >> 4) * 8 + i;
            float v = (r < 40) ? xp_w[(g * 40 + r) * 256 + e] : 0.f;
            WXP[u] = f2bf(v);
        }
    }
    // out-proj pack: thread handles 8 consecutive e
    {
        short8* WOUT8 = (short8*)(void*)(S + OFF_WOUT);
        for (int u = base; u < 4 * 128 * 32; u += pstride) {
            int g = u >> 12;
            int j = (u >> 5) & 127;
            int e8 = u & 31;
            const float4* src = (const float4*)(outp_w + ((size_t)(g * 128 + j)) * 256 + e8 * 8);
            float arr[8];
            *(float4*)&arr[0] = src[0];
            *(float4*)&arr[4] = src[1];
            short8 h8;
            #pragma unroll
            for (int jj = 0; jj < 8; jj++) h8[jj] = f2bf(arr[jj]);
            int ks = e8 >> 2;
            int lane = (j & 15) + 16 * (e8 & 3);
            int du8 = ((g * 8 + (j >> 4)) * 8 + ks) * 64 + lane;
            WOUT8[du8] = h8;
        }
    }
    for (int i = base; i < 32 * 512; i += pstride) {
        int c = i / 512, d = i % 512;
        S[OFF_HETT + d * 32 + c] = het_w[i];
        S[OFF_OWT  + d * 32 + c] = ow[i];
    }
    for (int i = base; i < 512 * 96; i += pstride) {
        int d = i / 96, r = i % 96;
        S[OFF_CWT + r * 512 + d] = conv_w[i];
    }
    for (int i = base; i < 512 * 4; i += pstride) {
        int d = i / 4, m = i % 4;
        S[OFF_TWT + m * 512 + d] = temp_w[i];
    }
    for (int i = base; i < 98 * 256; i += pstride) {
        int ii = i >> 8, q = i & 255;
        int l = (ii == 97) ? 0 : (927 + ii);
        float div = __expf((float)(2 * q) * (-LN10000 / 512.f));
        float sv, cv;
        sincosf((float)l * div, &sv, &cv);
        S[OFF_PE + ii * 512 + 2 * q]     = sv;
        S[OFF_PE + ii * 512 + 2 * q + 1] = cv;
    }
    for (int i = base; i < 4 * 16 * 256; i += pstride) {
        int g = i >> 12, n = (i >> 8) & 15, e = i & 255;
        S[OFF_A2T + i] = -__expf(A_log[(g * 256 + e) * 16 + n]);
    }
    for (int i = base; i < 4 * 1024; i += pstride) {
        int k = i >> 10, ge = i & 1023;
        S[OFF_CW1T + i] = conv1_w[ge * 4 + k];
    }
    for (int i = base; i < 8 * 1024; i += pstride) {
        int r = i >> 10, ge = i & 1023;
        S[OFF_DTWT + i] = dt_w[ge * 8 + r];
    }
}

// ---------------- kernel 1: e1 + scale, NP1 positions per block -------------
#define NP1 7
__global__ __launch_bounds__(256) void k_e1(float* S,
                                            const float* __restrict__ x_enc,
                                            const float* __restrict__ mark,
                                            const float* __restrict__ het_b) {
    int bx = blockIdx.x, b = blockIdx.y;
    int tid = threadIdx.x;
    __shared__ __align__(16) float xsf[NP1][96];
    __shared__ float mk[NP1][4];
    __shared__ __align__(16) float e1s[NP1][512];
    __shared__ float red3[8][NP1][32];
    __shared__ float smean[32], sistd[32];
    stats_load(S, b, tid, smean, sistd, nullptr);
    __syncthreads();
    for (int i = tid; i < NP1 * 96; i += 256) {
        int ip = i / 96, r = i - ip * 96;
        int k = r >> 5, c = r & 31;
        int ii = bx * NP1 + ip;
        int l = (ii == 97) ? 0 : (927 + ii);
        int la = l - 1 + k;
        la = (la < 0) ? la + 1024 : ((la >= 1024) ? la - 1024 : la);
        xsf[ip][c * 3 + k] = (x_enc[((size_t)b * 1024 + la) * 32 + c] - smean[c]) * sistd[c];
    }
    if (tid < NP1 * 4) {
        int ip = tid >> 2, m = tid & 3;
        int ii = bx * NP1 + ip;
        int l = (ii == 97) ? 0 : (927 + ii);
        mk[ip][m] = mark[((size_t)b * 1024 + l) * 4 + m];
    }
    __syncthreads();

    const float2* cw2 = (const float2*)(S + OFF_CWT);
    const float2* tw2 = (const float2*)(S + OFF_TWT);
    const float2* pe2 = (const float2*)(S + OFF_PE);
    float acc0[NP1], acc1[NP1];
    #pragma unroll
    for (int ip = 0; ip < NP1; ip++) { acc0[ip] = 0.f; acc1[ip] = 0.f; }
    #pragma unroll 2
    for (int j4 = 0; j4 < 24; j4++) {
        float2 w0 = cw2[(j4 * 4 + 0) * 256 + tid];
        float2 w1 = cw2[(j4 * 4 + 1) * 256 + tid];
        float2 w2 = cw2[(j4 * 4 + 2) * 256 + tid];
        float2 w3 = cw2[(j4 * 4 + 3) * 256 + tid];
        #pragma unroll
        for (int ip = 0; ip < NP1; ip++) {
            float4 xv = ((const float4*)&xsf[ip][0])[j4];
            acc0[ip] += xv.x * w0.x + xv.y * w1.x + xv.z * w2.x + xv.w * w3.x;
            acc1[ip] += xv.x * w0.y + xv.y * w1.y + xv.z * w2.y + xv.w * w3.y;
        }
    }
    #pragma unroll
    for (int m = 0; m < 4; m++) {
        float2 w = tw2[m * 256 + tid];
        #pragma unroll
        for (int ip = 0; ip < NP1; ip++) {
            acc0[ip] += mk[ip][m] * w.x;
            acc1[ip] += mk[ip][m] * w.y;
        }
    }
    #pragma unroll
    for (int ip = 0; ip < NP1; ip++) {
        int ii = bx * NP1 + ip;
        float2 pe = pe2[ii * 256 + tid];
        float t0 = acc0[ip] + pe.x, t1 = acc1[ip] + pe.y;
        e1s[ip][2 * tid] = t0; e1s[ip][2 * tid + 1] = t1;
        float2 e1o; e1o.x = t0; e1o.y = t1;
        ((float2*)(S + OFF_E1))[((size_t)b * 98 + ii) * 256 + tid] = e1o;
    }
    __syncthreads();

    int c = tid & 31, part = tid >> 5;
    const float* hetT = S + OFF_HETT;
    float p[NP1];
    #pragma unroll
    for (int ip = 0; ip < NP1; ip++) p[ip] = 0.f;
    #pragma unroll 8
    for (int d = 0; d < 64; d++) {
        float w = hetT[(part * 64 + d) * 32 + c];
        #pragma unroll
        for (int ip = 0; ip < NP1; ip++) p[ip] += e1s[ip][part * 64 + d] * w;
    }
    #pragma unroll
    for (int ip = 0; ip < NP1; ip++) red3[part][ip][c] = p[ip];
    __syncthreads();
    int ipp = tid >> 5;
    if (ipp < NP1) {
        float Sm = het_b[c];
        #pragma unroll
        for (int i = 0; i < 8; i++) Sm += red3[i][ipp][c];
        S[OFF_SCALE + ((size_t)b * 98 + bx * NP1 + ipp) * 32 + c] = __expf(Sm);
    }
}

// ---------------- kernel 2: xc = e1 + e2, NP2 positions per block -----------
#define NP2 8
__global__ __launch_bounds__(256) void k_xc(float* S,
                                            const float* __restrict__ x_enc,
                                            const float* __restrict__ mark) {
    int bx = blockIdx.x, b = blockIdx.y;
    int tid = threadIdx.x;
    __shared__ __align__(16) float xsf[NP2][96];
    __shared__ float mk[NP2][4];
    __shared__ float smean[32], sistd[32];
    stats_load(S, b, tid, smean, sistd, nullptr);
    __syncthreads();
    for (int i = tid; i < NP2 * 96; i += 256) {
        int ip = i / 96, r = i - ip * 96;
        int k = r >> 5, c = r & 31;
        int s = bx * NP2 + ip;
        int l = 928 + s;
        int la = l - 1 + k;
        if (la >= 1024) la -= 1024;
        int idx = (la == 0) ? 97 : (la - 927);
        float xn = (x_enc[((size_t)b * 1024 + la) * 32 + c] - smean[c]) * sistd[c];
        xsf[ip][c * 3 + k] = xn * S[OFF_SCALE + ((size_t)b * 98 + idx) * 32 + c];
    }
    if (tid < NP2 * 4) {
        int ip = tid >> 2, m = tid & 3;
        int l = 928 + bx * NP2 + ip;
        mk[ip][m] = mark[((size_t)b * 1024 + l) * 4 + m];
    }
    __syncthreads();

    const float2* cw2 = (const float2*)(S + OFF_CWT);
    const float2* tw2 = (const float2*)(S + OFF_TWT);
    const float2* pe2 = (const float2*)(S + OFF_PE);
    float acc0[NP2], acc1[NP2];
    #pragma unroll
    for (int ip = 0; ip < NP2; ip++) { acc0[ip] = 0.f; acc1[ip] = 0.f; }
    #pragma unroll 2
    for (int j4 = 0; j4 < 24; j4++) {
        float2 w0 = cw2[(j4 * 4 + 0) * 256 + tid];
        float2 w1 = cw2[(j4 * 4 + 1) * 256 + tid];
        float2 w2 = cw2[(j4 * 4 + 2) * 256 + tid];
        float2 w3 = cw2[(j4 * 4 + 3) * 256 + tid];
        #pragma unroll
        for (int ip = 0; ip < NP2; ip++) {
            float4 xv = ((const float4*)&xsf[ip][0])[j4];
            acc0[ip] += xv.x * w0.x + xv.y * w1.x + xv.z * w2.x + xv.w * w3.x;
            acc1[ip] += xv.x * w0.y + xv.y * w1.y + xv.z * w2.y + xv.w * w3.y;
        }
    }
    #pragma unroll
    for (int m = 0; m < 4; m++) {
        float2 w = tw2[m * 256 + tid];
        #pragma unroll
        for (int ip = 0; ip < NP2; ip++) {
            acc0[ip] += mk[ip][m] * w.x;
            acc1[ip] += mk[ip][m] * w.y;
        }
    }
    #pragma unroll
    for (int ip = 0; ip < NP2; ip++) {
        int s = bx * NP2 + ip;
        float2 pe = pe2[(s + 1) * 256 + tid];
        float2 e1v = ((const float2*)(S + OFF_E1))[((size_t)b * 98 + (s + 1)) * 256 + tid];
        float2 o;
        o.x = acc0[ip] + pe.x + e1v.x;
        o.y = acc1[ip] + pe.y + e1v.y;
        ((float2*)(S + OFF_XC))[((size_t)b * 96 + s) * 256 + tid] = o;
    }
}

// ---------------- kernel 3: mamba per (g, b, patch), MFMA -------------------
// Fragment convention (identical bijection for A and B packing):
//   A: lane = row + 16*q holds A[row][ks*32 + q*8 + i]
//   B: lane = col + 16*q holds B[ks*32 + q*8 + i][col]
//   D (HW-verified): lane holds D[(lane>>4)*4 + reg][lane&15]
__global__ __launch_bounds__(256, 3) void k_mamba(float* S,
                                                  const float* __restrict__ conv1_b,
                                                  const float* __restrict__ dt_b,
                                                  const float* __restrict__ Dp) {
    int p = blockIdx.x, b = blockIdx.y, g = blockIdx.z;
    int tid = threadIdx.x;
    int l = tid & 63, w = tid >> 6;
    int lt = l & 15, lq = l >> 4;

    __shared__ __align__(16) short uplane[8192];   // x_hi/x_lo; then xq_hi; y_hi
    __shared__ float xz[512 * 17];                 // [n][t]: n<256 a0, n>=256 z
    __shared__ __align__(16) float dtraw[16 * 8];
    __shared__ __align__(16) float Bm[16 * 20], Cm[16 * 20];

    // ---- A: load x tile, split hi/lo bf16 into swizzled planes ----
    {
        const float* xg = S + OFF_XC + ((size_t)b * 96 + p * 16) * 512 + g * 128;
        #pragma unroll
        for (int it = 0; it < 8; it++) {
            int i = it * 256 + tid;
            int t = i >> 7, j = i & 127;
            float v = xg[t * 512 + j];
            short hi = f2bf(v);
            short lo = f2bf(v - bf2f_s(hi));
            int bo = t * 256 + ((j * 2) ^ ((t & 7) << 4));
            uplane[bo >> 1] = hi;
            uplane[2048 + (bo >> 1)] = lo;
        }
    }
    __syncthreads();

    // ---- B: in-proj via MFMA, double-buffered weight prefetch ----
    {
        short8 ah[4], al[4];
        #pragma unroll
        for (int ks = 0; ks < 4; ks++) {
            int c = (ks * 32 + lq * 8) * 2;
            int bo = lt * 256 + (c ^ ((lt & 7) << 4));
            ah[ks] = *(const short8*)((const char*)uplane + bo);
            al[ks] = *(const short8*)((const char*)uplane + 4096 + bo);
        }
        const short8* WF = (const short8*)(const void*)(S + OFF_WIN);
        const int fbase = (g * 32 + w * 8) * 512 + l;   // nt stride 512, ks stride 128, lo +64
        short8 wh[2][4], wl[2][4];
        #pragma unroll
        for (int ks = 0; ks < 4; ks++) {
            wh[0][ks] = WF[fbase + ks * 128];
            wl[0][ks] = WF[fbase + ks * 128 + 64];
        }
        #pragma unroll
        for (int ntl = 0; ntl < 8; ntl++) {
            int cur = ntl & 1, nxt = cur ^ 1;
            if (ntl < 7) {
                #pragma unroll
                for (int ks = 0; ks < 4; ks++) {
                    wh[nxt][ks] = WF[fbase + (ntl + 1) * 512 + ks * 128];
                    wl[nxt][ks] = WF[fbase + (ntl + 1) * 512 + ks * 128 + 64];
                }
            }
            float4v acc = {0.f, 0.f, 0.f, 0.f};
            #pragma unroll
            for (int ks = 0; ks < 4; ks++) {
                acc = __builtin_amdgcn_mfma_f32_16x16x32_bf16(ah[ks], wh[cur][ks], acc, 0, 0, 0);
                acc = __builtin_amdgcn_mfma_f32_16x16x32_bf16(al[ks], wh[cur][ks], acc, 0, 0, 0);
                acc = __builtin_amdgcn_mfma_f32_16x16x32_bf16(ah[ks], wl[cur][ks], acc, 0, 0, 0);
            }
            int n = (w * 8 + ntl) * 16 + lt;
            int t0 = lq * 4;
            #pragma unroll
            for (int r = 0; r < 4; r++) xz[n * 17 + t0 + r] = acc[r];
        }
    }
    __syncthreads();

    // ---- C: depthwise conv(4) + silu (regs), publish xq_hi plane ----
    float xq[16];
    {
        int e = tid, ge = g * 256 + e;
        float ar[16];
        #pragma unroll
        for (int t = 0; t < 16; t++) ar[t] = xz[e * 17 + t];
        float w0 = S[OFF_CW1T + 0 * 1024 + ge];
        float w1 = S[OFF_CW1T + 1 * 1024 + ge];
        float w2 = S[OFF_CW1T + 2 * 1024 + ge];
        float w3 = S[OFF_CW1T + 3 * 1024 + ge];
        float bb = conv1_b[ge];
        #pragma unroll
        for (int t = 0; t < 16; t++) {
            float sa = bb + w3 * ar[t];
            if (t >= 1) sa += w2 * ar[t - 1];
            if (t >= 2) sa += w1 * ar[t - 2];
            if (t >= 3) sa += w0 * ar[t - 3];
            xq[t] = sa * (1.f / (1.f + __expf(-sa)));
        }
        #pragma unroll
        for (int t = 0; t < 16; t++) {
            int bo = t * 512 + ((e * 2) ^ ((t & 7) << 4));
            uplane[bo >> 1] = f2bf(xq[t]);
        }
    }
    __syncthreads();

    // ---- D: x-proj via MFMA (hi only), waves 0..2, weights preloaded ----
    if (w < 3) {
        const short8* WXF = (const short8*)(const void*)(S + OFF_WXP);
        short8 wx[8];
        #pragma unroll
        for (int ks = 0; ks < 8; ks++) wx[ks] = WXF[((g * 3 + w) * 8 + ks) * 64 + l];
        float4v acc = {0.f, 0.f, 0.f, 0.f};
        #pragma unroll
        for (int ks = 0; ks < 8; ks++) {
            int c = (ks * 32 + lq * 8) * 2;
            int bo = lt * 512 + (c ^ ((lt & 7) << 4));
            short8 a = *(const short8*)((const char*)uplane + bo);
            acc = __builtin_amdgcn_mfma_f32_16x16x32_bf16(a, wx[ks], acc, 0, 0, 0);
        }
        int r = w * 16 + lt;
        if (r < 40) {
            int t0 = lq * 4;
            #pragma unroll
            for (int rr = 0; rr < 4; rr++) {
                float v = acc[rr];
                int t = t0 + rr;
                if (r < 8) dtraw[t * 8 + r] = v;
                else if (r < 24) Bm[t * 20 + (r - 8)] = v;
                else Cm[t * 20 + (r - 24)] = v;
            }
        }
    }
    __syncthreads();

    // ---- E+F: dt + selective scan (regs), publish y_hi plane ----
    {
        int e = tid, ge = g * 256 + e;
        float Av[16];
        #pragma unroll
        for (int n = 0; n < 16; n++) Av[n] = S[OFF_A2T + (g * 16 + n) * 256 + e];
        float dtw[8];
        #pragma unroll
        for (int r = 0; r < 8; r++) dtw[r] = S[OFF_DTWT + r * 1024 + ge];
        float dtbv = dt_b[ge];
        float Dv = Dp[ge];
        float h[16];
        #pragma unroll
        for (int n = 0; n < 16; n++) h[n] = 0.f;
        for (int t = 0; t < 16; t++) {
            const float4* q = (const float4*)&dtraw[t * 8];
            float4 q0 = q[0], q1 = q[1];
            float sa = dtbv + q0.x * dtw[0] + q0.y * dtw[1] + q0.z * dtw[2] + q0.w * dtw[3]
                            + q1.x * dtw[4] + q1.y * dtw[5] + q1.z * dtw[6] + q1.w * dtw[7];
            // softplus via fast log/exp: max(sa,0) + log(1 + exp(-|sa|))
            float dtv = fmaxf(sa, 0.f) + __logf(1.f + __expf(-fabsf(sa)));
            float Bl[16], Cl[16];
            {
                const float4* b4 = (const float4*)&Bm[t * 20];
                *(float4*)&Bl[0] = b4[0]; *(float4*)&Bl[4] = b4[1];
                *(float4*)&Bl[8] = b4[2]; *(float4*)&Bl[12] = b4[3];
                const float4* c4p = (const float4*)&Cm[t * 20];
                *(float4*)&Cl[0] = c4p[0]; *(float4*)&Cl[4] = c4p[1];
                *(float4*)&Cl[8] = c4p[2]; *(float4*)&Cl[12] = c4p[3];
            }
            float xv = xq[t];
            float dx = dtv * xv;
            float y = 0.f;
            #pragma unroll
            for (int n = 0; n < 16; n++) {
                h[n] = __expf(dtv * Av[n]) * h[n] + dx * Bl[n];
                y += h[n] * Cl[n];
            }
            y += Dv * xv;
            float zv = xz[(256 + e) * 17 + t];
            y *= zv * (1.f / (1.f + __expf(-zv)));
            int bo = t * 512 + ((e * 2) ^ ((t & 7) << 4));
            uplane[4096 + (bo >> 1)] = f2bf(y);
        }
    }
    __syncthreads();

    // ---- G: out-proj via MFMA (hi only), 2 n-tiles/wave, prefetched ----
    {
        const short8* WOF = (const short8*)(const void*)(S + OFF_WOUT);
        const int gb = (g * 8 + w * 2) * 512 + l;   // nt stride 512, ks stride 64
        short8 wo[2][8];
        #pragma unroll
        for (int ks = 0; ks < 8; ks++) wo[0][ks] = WOF[gb + ks * 64];
        #pragma unroll
        for (int ntl = 0; ntl < 2; ntl++) {
            if (ntl == 0) {
                #pragma unroll
                for (int ks = 0; ks < 8; ks++) wo[1][ks] = WOF[gb + 512 + ks * 64];
            }
            float4v acc = {0.f, 0.f, 0.f, 0.f};
            #pragma unroll
            for (int ks = 0; ks < 8; ks++) {
                int c = (ks * 32 + lq * 8) * 2;
                int bo = 8192 + lt * 512 + (c ^ ((lt & 7) << 4));
                short8 a = *(const short8*)((const char*)uplane + bo);
                acc = __builtin_amdgcn_mfma_f32_16x16x32_bf16(a, wo[ntl][ks], acc, 0, 0, 0);
            }
            int j = (w * 2 + ntl) * 16 + lt;
            int t0 = lq * 4;
            float* XM = S + OFF_XM + ((size_t)b * 96 + p * 16 + t0) * 512 + g * 128 + j;
            #pragma unroll
            for (int rr = 0; rr < 4; rr++) XM[rr * 512] = acc[rr];
        }
    }
}

// ---------------- kernel 4: final projection + de-normalize, 8 pos/block ----
#define NPO 8
__global__ __launch_bounds__(256) void k_out(float* S, float* __restrict__ out) {
    int bx = blockIdx.x, b = blockIdx.y;   // grid (12, 32)
    int tid = threadIdx.x;
    int c = tid & 31, part = tid >> 5;     // 8 parts x 64 d
    __shared__ __align__(16) float xls[NPO][512];
    __shared__ float red[8][NPO][32];
    __shared__ float smean[32], sstd[32];
    stats_load(S, b, tid, smean, nullptr, sstd);
    for (int i = tid; i < NPO * 512; i += 256) {
        int ip = i >> 9, d = i & 511;
        xls[ip][d] = S[OFF_XM + ((size_t)b * 96 + bx * NPO + ip) * 512 + d];
    }
    __syncthreads();
    const float* owT = S + OFF_OWT;
    float acc[NPO];
    #pragma unroll
    for (int ip = 0; ip < NPO; ip++) acc[ip] = 0.f;
    #pragma unroll 8
    for (int d = 0; d < 64; d++) {
        float w = owT[(part * 64 + d) * 32 + c];
        #pragma unroll
        for (int ip = 0; ip < NPO; ip++) acc[ip] += xls[ip][part * 64 + d] * w;
    }
    #pragma unroll
    for (int ip = 0; ip < NPO; ip++) red[part][ip][c] = acc[ip];
    __syncthreads();
    int ipo = tid >> 5;
    float Sm = 0.f;
    #pragma unroll
    for (int i = 0; i < 8; i++) Sm += red[i][ipo][c];
    int s = bx * NPO + ipo;
    out[((size_t)b * 96 + s) * 32 + c] = Sm * sstd[c] + smean[c];
}

extern "C" void kernel_launch(void* const* d_in, const int* in_sizes, int n_in,
                              void* d_out, int out_size, void* d_ws, size_t ws_size,
                              hipStream_t stream) {
    (void)in_sizes; (void)n_in; (void)out_size;
    const float* x_enc   = (const float*)d_in[0];
    const float* mark    = (const float*)d_in[1];
    const float* conv_w  = (const float*)d_in[4];
    const float* temp_w  = (const float*)d_in[5];
    const float* het_w   = (const float*)d_in[6];
    const float* het_b   = (const float*)d_in[7];
    const float* in_proj = (const float*)d_in[8];
    const float* conv1_w = (const float*)d_in[9];
    const float* conv1_b = (const float*)d_in[10];
    const float* xp_w    = (const float*)d_in[11];
    const float* dt_w    = (const float*)d_in[12];
    const float* dt_b    = (const float*)d_in[13];
    const float* A_log   = (const float*)d_in[14];
    const float* D_param = (const float*)d_in[15];
    const float* outp_w  = (const float*)d_in[16];
    const float* ow      = (const float*)d_in[17];
    float* out = (float*)d_out;

    float* S = (float*)d_ws;
    if (ws_size < (size_t)WS_FLOATS * sizeof(float)) {
        void* p = nullptr;
        hipGetSymbolAddress(&p, HIP_SYMBOL(g_fb));
        S = (float*)p;
    }

    k_stats<<<dim3(8, 32), dim3(256), 0, stream>>>(S, x_enc);
    k_prep<<<dim3(256), dim3(256), 0, stream>>>(S, in_proj, outp_w, xp_w, het_w, ow,
                                                conv_w, temp_w, A_log, conv1_w, dt_w);
    k_e1<<<dim3(14, 32), dim3(256), 0, stream>>>(S, x_enc, mark, het_b);
    k_xc<<<dim3(12, 32), dim3(256), 0, stream>>>(S, x_enc, mark);
    k_mamba<<<dim3(6, 32, 4), dim3(256), 0, stream>>>(S, conv1_b, dt_b, D_param);
    k_out<<<dim3(12, 32), dim3(256), 0, stream>>>(S, out);
}

// Round 7
// 92.272 us; speedup vs baseline: 3.2375x; 1.1590x over previous
//
#include <hip/hip_runtime.h>
#include <hip/hip_bf16.h>
#include <math.h>

#define LN10000 9.210340371976184f

typedef __attribute__((ext_vector_type(8))) short short8;
typedef __attribute__((ext_vector_type(4))) short short4v;
typedef __attribute__((ext_vector_type(4))) float float4v;

// ---- scratch layout (float offsets into workspace) ----
#define OFF_E1     3072              // 32*98*512
#define OFF_SCALE  1608704           // 32*98*32
#define OFF_XC     1709056           // 32*96*512
#define OFF_XM     3281920           // 32*96*512
#define OFF_WIN    4854784           // in-proj frags: 4g*32nt*4ks*2hl*512 ushort = 262144 fl
#define OFF_WXP    5116928           // x-proj frags: 4g*3nt*8ks*512 ushort = 24576 fl
#define OFF_WOUT   5141504           // out-proj frags: 4g*8nt*8ks*512 ushort = 65536 fl
#define OFF_HETT   5207040           // 512*32 [d][c]
#define OFF_OWT    5223424           // 512*32 [d][c]
#define OFF_CWT    5239808           // 96*512 [c*3+k][d]
#define OFF_TWT    5288960           // 4*512  [m][d]
#define OFF_PE     5291008           // 98*512 [ii][d]
#define OFF_A2T    5341184           // 4*16*256 [g][n][e] = -exp(A_log)
#define OFF_CW1T   5357568           // 4*1024 [k][g*256+e]
#define OFF_DTWT   5361664           // 8*1024 [r][g*256+e]
#define OFF_SPART  5369856           // 32b*8sub*64 (s[32], q[32]) partial stats
#define WS_FLOATS  5386240

__device__ float g_fb[WS_FLOATS];    // fallback if ws_size too small

__device__ inline short f2bf(float x) {
    __hip_bfloat16 h = __float2bfloat16(x);
    return *reinterpret_cast<short*>(&h);
}
__device__ inline float bf2f_s(short s) {
    __hip_bfloat16 h = *reinterpret_cast<__hip_bfloat16*>(&s);
    return __bfloat162float(h);
}

// each consumer block reduces the 8 stats partials itself (16 L2 loads)
__device__ inline void stats_load(const float* S, int b, int tid,
                                  float* sm, float* si, float* sd) {
    if (tid < 32) {
        float s = 0.f, q = 0.f;
        #pragma unroll
        for (int i = 0; i < 8; i++) {
            s += S[OFF_SPART + ((b * 8 + i) << 6) + tid];
            q += S[OFF_SPART + ((b * 8 + i) << 6) + 32 + tid];
        }
        float m = s * (1.f / 1024.f);
        float var = q * (1.f / 1024.f) - m * m;
        float sdv = sqrtf(var + 1e-5f);
        sm[tid] = m;
        if (si) si[tid] = 1.f / sdv;
        if (sd) sd[tid] = sdv;
    }
}

// ---------------- kernel 0: pack (blocks 0..255) + stats (256..511) ---------
__global__ __launch_bounds__(256) void k_prep(float* S,
                                              const float* __restrict__ x,
                                              const float* __restrict__ in_w,
                                              const float* __restrict__ outp_w,
                                              const float* __restrict__ xp_w,
                                              const float* __restrict__ het_w,
                                              const float* __restrict__ ow,
                                              const float* __restrict__ conv_w,
                                              const float* __restrict__ temp_w,
                                              const float* __restrict__ A_log,
                                              const float* __restrict__ conv1_w,
                                              const float* __restrict__ dt_w) {
    if (blockIdx.x >= 256) {
        // ---- stats partials: bxs -> (b, sub) ----
        int bxs = blockIdx.x - 256;
        int sub = bxs & 7, b = bxs >> 3;
        int tid = threadIdx.x;
        int c4 = tid & 7, rl = tid >> 3;
        const float4* xb = (const float4*)(x + (size_t)b * 32768) + c4;
        float s0 = 0.f, s1 = 0.f, s2 = 0.f, s3 = 0.f;
        float q0 = 0.f, q1 = 0.f, q2 = 0.f, q3 = 0.f;
        #pragma unroll
        for (int i = 0; i < 4; i++) {
            int l = sub * 128 + rl + i * 32;
            float4 v = xb[l * 8];
            s0 += v.x; q0 += v.x * v.x;
            s1 += v.y; q1 += v.y * v.y;
            s2 += v.z; q2 += v.z * v.z;
            s3 += v.w; q3 += v.w * v.w;
        }
        __shared__ float rs[32][33], rq[32][33];
        rs[rl][c4 * 4 + 0] = s0; rq[rl][c4 * 4 + 0] = q0;
        rs[rl][c4 * 4 + 1] = s1; rq[rl][c4 * 4 + 1] = q1;
        rs[rl][c4 * 4 + 2] = s2; rq[rl][c4 * 4 + 2] = q2;
        rs[rl][c4 * 4 + 3] = s3; rq[rl][c4 * 4 + 3] = q3;
        __syncthreads();
        if (tid < 32) {
            float s = 0.f, q = 0.f;
            #pragma unroll
            for (int i = 0; i < 32; i++) { s += rs[i][tid]; q += rq[i][tid]; }
            S[OFF_SPART + ((b * 8 + sub) << 6) + tid] = s;
            S[OFF_SPART + ((b * 8 + sub) << 6) + 32 + tid] = q;
        }
        return;
    }
    const int base = blockIdx.x * 256 + threadIdx.x;
    const int pstride = 256 << 8;

    // in-proj pack: thread handles 8 consecutive k (one short8 per plane)
    {
        short8* WIN8 = (short8*)(void*)(S + OFF_WIN);
        for (int u = base; u < 4 * 512 * 16; u += pstride) {
            int g = u >> 13;
            int n = (u >> 4) & 511;
            int k8 = u & 15;
            const float4* src = (const float4*)(in_w + ((size_t)(g * 512 + n)) * 128 + k8 * 8);
            float arr[8];
            *(float4*)&arr[0] = src[0];
            *(float4*)&arr[4] = src[1];
            short8 h8, l8;
            #pragma unroll
            for (int j = 0; j < 8; j++) {
                short hi = f2bf(arr[j]);
                h8[j] = hi;
                l8[j] = f2bf(arr[j] - bf2f_s(hi));
            }
            int ks = k8 >> 2;
            int lane = (n & 15) + 16 * (k8 & 3);
            int du8 = (((g * 32 + (n >> 4)) * 4 + ks) * 2) * 64 + lane;
            WIN8[du8] = h8;
            WIN8[du8 + 64] = l8;
        }
    }
    // x-proj pack, dest-ordered (small, zero-fill rows 40..47)
    {
        short* WXP = (short*)(void*)(S + OFF_WXP);
        for (int u = base; u < 4 * 3 * 8 * 512; u += pstride) {
            int i = u & 7;
            int lane = (u >> 3) & 63;
            int ks = (u >> 9) & 7;
            int rest = u >> 12;
            int g = rest / 3, nt = rest % 3;
            int r = nt * 16 + (lane & 15);
            int e = ks * 32 + (lane >> 4) * 8 + i;
            float v = (r < 40) ? xp_w[(g * 40 + r) * 256 + e] : 0.f;
            WXP[u] = f2bf(v);
        }
    }
    // out-proj pack: thread handles 8 consecutive e
    {
        short8* WOUT8 = (short8*)(void*)(S + OFF_WOUT);
        for (int u = base; u < 4 * 128 * 32; u += pstride) {
            int g = u >> 12;
            int j = (u >> 5) & 127;
            int e8 = u & 31;
            const float4* src = (const float4*)(outp_w + ((size_t)(g * 128 + j)) * 256 + e8 * 8);
            float arr[8];
            *(float4*)&arr[0] = src[0];
            *(float4*)&arr[4] = src[1];
            short8 h8;
            #pragma unroll
            for (int jj = 0; jj < 8; jj++) h8[jj] = f2bf(arr[jj]);
            int ks = e8 >> 2;
            int lane = (j & 15) + 16 * (e8 & 3);
            int du8 = ((g * 8 + (j >> 4)) * 8 + ks) * 64 + lane;
            WOUT8[du8] = h8;
        }
    }
    for (int i = base; i < 32 * 512; i += pstride) {
        int c = i / 512, d = i % 512;
        S[OFF_HETT + d * 32 + c] = het_w[i];
        S[OFF_OWT  + d * 32 + c] = ow[i];
    }
    for (int i = base; i < 512 * 96; i += pstride) {
        int d = i / 96, r = i % 96;
        S[OFF_CWT + r * 512 + d] = conv_w[i];
    }
    for (int i = base; i < 512 * 4; i += pstride) {
        int d = i / 4, m = i % 4;
        S[OFF_TWT + m * 512 + d] = temp_w[i];
    }
    for (int i = base; i < 98 * 256; i += pstride) {
        int ii = i >> 8, q = i & 255;
        int l = (ii == 97) ? 0 : (927 + ii);
        float div = __expf((float)(2 * q) * (-LN10000 / 512.f));
        float sv, cv;
        sincosf((float)l * div, &sv, &cv);
        S[OFF_PE + ii * 512 + 2 * q]     = sv;
        S[OFF_PE + ii * 512 + 2 * q + 1] = cv;
    }
    for (int i = base; i < 4 * 16 * 256; i += pstride) {
        int g = i >> 12, n = (i >> 8) & 15, e = i & 255;
        S[OFF_A2T + i] = -__expf(A_log[(g * 256 + e) * 16 + n]);
    }
    for (int i = base; i < 4 * 1024; i += pstride) {
        int k = i >> 10, ge = i & 1023;
        S[OFF_CW1T + i] = conv1_w[ge * 4 + k];
    }
    for (int i = base; i < 8 * 1024; i += pstride) {
        int r = i >> 10, ge = i & 1023;
        S[OFF_DTWT + i] = dt_w[ge * 8 + r];
    }
}

// ---------------- kernel 1: e1 + scale, NP1 positions per block -------------
#define NP1 7
__global__ __launch_bounds__(256) void k_e1(float* S,
                                            const float* __restrict__ x_enc,
                                            const float* __restrict__ mark,
                                            const float* __restrict__ het_b) {
    int bx = blockIdx.x, b = blockIdx.y;
    int tid = threadIdx.x;
    __shared__ __align__(16) float xsf[NP1][96];
    __shared__ float mk[NP1][4];
    __shared__ __align__(16) float e1s[NP1][512];
    __shared__ float red3[8][NP1][32];
    __shared__ float smean[32], sistd[32];
    stats_load(S, b, tid, smean, sistd, nullptr);
    __syncthreads();
    for (int i = tid; i < NP1 * 96; i += 256) {
        int ip = i / 96, r = i - ip * 96;
        int k = r >> 5, c = r & 31;
        int ii = bx * NP1 + ip;
        int l = (ii == 97) ? 0 : (927 + ii);
        int la = l - 1 + k;
        la = (la < 0) ? la + 1024 : ((la >= 1024) ? la - 1024 : la);
        xsf[ip][c * 3 + k] = (x_enc[((size_t)b * 1024 + la) * 32 + c] - smean[c]) * sistd[c];
    }
    if (tid < NP1 * 4) {
        int ip = tid >> 2, m = tid & 3;
        int ii = bx * NP1 + ip;
        int l = (ii == 97) ? 0 : (927 + ii);
        mk[ip][m] = mark[((size_t)b * 1024 + l) * 4 + m];
    }
    __syncthreads();

    const float2* cw2 = (const float2*)(S + OFF_CWT);
    const float2* tw2 = (const float2*)(S + OFF_TWT);
    const float2* pe2 = (const float2*)(S + OFF_PE);
    float acc0[NP1], acc1[NP1];
    #pragma unroll
    for (int ip = 0; ip < NP1; ip++) { acc0[ip] = 0.f; acc1[ip] = 0.f; }
    #pragma unroll 2
    for (int j4 = 0; j4 < 24; j4++) {
        float2 w0 = cw2[(j4 * 4 + 0) * 256 + tid];
        float2 w1 = cw2[(j4 * 4 + 1) * 256 + tid];
        float2 w2 = cw2[(j4 * 4 + 2) * 256 + tid];
        float2 w3 = cw2[(j4 * 4 + 3) * 256 + tid];
        #pragma unroll
        for (int ip = 0; ip < NP1; ip++) {
            float4 xv = ((const float4*)&xsf[ip][0])[j4];
            acc0[ip] += xv.x * w0.x + xv.y * w1.x + xv.z * w2.x + xv.w * w3.x;
            acc1[ip] += xv.x * w0.y + xv.y * w1.y + xv.z * w2.y + xv.w * w3.y;
        }
    }
    #pragma unroll
    for (int m = 0; m < 4; m++) {
        float2 w = tw2[m * 256 + tid];
        #pragma unroll
        for (int ip = 0; ip < NP1; ip++) {
            acc0[ip] += mk[ip][m] * w.x;
            acc1[ip] += mk[ip][m] * w.y;
        }
    }
    #pragma unroll
    for (int ip = 0; ip < NP1; ip++) {
        int ii = bx * NP1 + ip;
        float2 pe = pe2[ii * 256 + tid];
        float t0 = acc0[ip] + pe.x, t1 = acc1[ip] + pe.y;
        e1s[ip][2 * tid] = t0; e1s[ip][2 * tid + 1] = t1;
        float2 e1o; e1o.x = t0; e1o.y = t1;
        ((float2*)(S + OFF_E1))[((size_t)b * 98 + ii) * 256 + tid] = e1o;
    }
    __syncthreads();

    int c = tid & 31, part = tid >> 5;
    const float* hetT = S + OFF_HETT;
    float p[NP1];
    #pragma unroll
    for (int ip = 0; ip < NP1; ip++) p[ip] = 0.f;
    #pragma unroll 8
    for (int d = 0; d < 64; d++) {
        float w = hetT[(part * 64 + d) * 32 + c];
        #pragma unroll
        for (int ip = 0; ip < NP1; ip++) p[ip] += e1s[ip][part * 64 + d] * w;
    }
    #pragma unroll
    for (int ip = 0; ip < NP1; ip++) red3[part][ip][c] = p[ip];
    __syncthreads();
    int ipp = tid >> 5;
    if (ipp < NP1) {
        float Sm = het_b[c];
        #pragma unroll
        for (int i = 0; i < 8; i++) Sm += red3[i][ipp][c];
        S[OFF_SCALE + ((size_t)b * 98 + bx * NP1 + ipp) * 32 + c] = __expf(Sm);
    }
}

// ---------------- kernel 2: xc = e1 + e2, NP2 positions per block -----------
#define NP2 8
__global__ __launch_bounds__(256) void k_xc(float* S,
                                            const float* __restrict__ x_enc,
                                            const float* __restrict__ mark) {
    int bx = blockIdx.x, b = blockIdx.y;
    int tid = threadIdx.x;
    __shared__ __align__(16) float xsf[NP2][96];
    __shared__ float mk[NP2][4];
    __shared__ float smean[32], sistd[32];
    stats_load(S, b, tid, smean, sistd, nullptr);
    __syncthreads();
    for (int i = tid; i < NP2 * 96; i += 256) {
        int ip = i / 96, r = i - ip * 96;
        int k = r >> 5, c = r & 31;
        int s = bx * NP2 + ip;
        int l = 928 + s;
        int la = l - 1 + k;
        if (la >= 1024) la -= 1024;
        int idx = (la == 0) ? 97 : (la - 927);
        float xn = (x_enc[((size_t)b * 1024 + la) * 32 + c] - smean[c]) * sistd[c];
        xsf[ip][c * 3 + k] = xn * S[OFF_SCALE + ((size_t)b * 98 + idx) * 32 + c];
    }
    if (tid < NP2 * 4) {
        int ip = tid >> 2, m = tid & 3;
        int l = 928 + bx * NP2 + ip;
        mk[ip][m] = mark[((size_t)b * 1024 + l) * 4 + m];
    }
    __syncthreads();

    const float2* cw2 = (const float2*)(S + OFF_CWT);
    const float2* tw2 = (const float2*)(S + OFF_TWT);
    const float2* pe2 = (const float2*)(S + OFF_PE);
    float acc0[NP2], acc1[NP2];
    #pragma unroll
    for (int ip = 0; ip < NP2; ip++) { acc0[ip] = 0.f; acc1[ip] = 0.f; }
    #pragma unroll 2
    for (int j4 = 0; j4 < 24; j4++) {
        float2 w0 = cw2[(j4 * 4 + 0) * 256 + tid];
        float2 w1 = cw2[(j4 * 4 + 1) * 256 + tid];
        float2 w2 = cw2[(j4 * 4 + 2) * 256 + tid];
        float2 w3 = cw2[(j4 * 4 + 3) * 256 + tid];
        #pragma unroll
        for (int ip = 0; ip < NP2; ip++) {
            float4 xv = ((const float4*)&xsf[ip][0])[j4];
            acc0[ip] += xv.x * w0.x + xv.y * w1.x + xv.z * w2.x + xv.w * w3.x;
            acc1[ip] += xv.x * w0.y + xv.y * w1.y + xv.z * w2.y + xv.w * w3.y;
        }
    }
    #pragma unroll
    for (int m = 0; m < 4; m++) {
        float2 w = tw2[m * 256 + tid];
        #pragma unroll
        for (int ip = 0; ip < NP2; ip++) {
            acc0[ip] += mk[ip][m] * w.x;
            acc1[ip] += mk[ip][m] * w.y;
        }
    }
    #pragma unroll
    for (int ip = 0; ip < NP2; ip++) {
        int s = bx * NP2 + ip;
        float2 pe = pe2[(s + 1) * 256 + tid];
        float2 e1v = ((const float2*)(S + OFF_E1))[((size_t)b * 98 + (s + 1)) * 256 + tid];
        float2 o;
        o.x = acc0[ip] + pe.x + e1v.x;
        o.y = acc1[ip] + pe.y + e1v.y;
        ((float2*)(S + OFF_XC))[((size_t)b * 96 + s) * 256 + tid] = o;
    }
}

// ---------------- kernel 3: mamba per (g, b, patch), MFMA, 4 blocks/CU ------
// Fragment convention (identical bijection for A and B packing):
//   A: lane = row + 16*q holds A[row][ks*32 + q*8 + i]
//   B: lane = col + 16*q holds B[ks*32 + q*8 + i][col]
//   D (HW-verified): lane holds D[(lane>>4)*4 + reg][lane&15]
// LDS overlay: uplane 8KB holds x_hi[0,4K)+x_lo[4K,8K) (phase A/B),
// then xq [0,8K) (C/D), then y [0,8K) (F/G). a0T t-major f32, zT t-major bf16.
#define A0S 265
#define ZS  273
__global__ __launch_bounds__(256, 4) void k_mamba(float* S,
                                                  const float* __restrict__ conv1_b,
                                                  const float* __restrict__ dt_b,
                                                  const float* __restrict__ Dp) {
    int p = blockIdx.x, b = blockIdx.y, g = blockIdx.z;
    int tid = threadIdx.x;
    int l = tid & 63, w = tid >> 6;
    int lt = l & 15, lq = l >> 4;

    __shared__ __align__(16) short uplane[4096];   // 8KB overlay
    __shared__ float a0T[16 * A0S];                // [t][e], 16.96KB
    __shared__ short zT[16 * ZS];                  // [t][e] bf16, 8.7KB
    __shared__ __align__(16) float dtraw[16 * 8];
    __shared__ __align__(16) float Bm[16 * 20], Cm[16 * 20];

    // ---- A: load x tile (float4), split hi/lo bf16 into swizzled planes ----
    {
        const float4* xg = (const float4*)(S + OFF_XC + ((size_t)b * 96 + p * 16) * 512 + g * 128);
        #pragma unroll
        for (int it = 0; it < 2; it++) {
            int i = it * 256 + tid;
            int t = i >> 5, j4 = i & 31;
            float4 v = xg[t * 128 + j4];
            float vv[4] = {v.x, v.y, v.z, v.w};
            short4v hs, ls;
            #pragma unroll
            for (int k = 0; k < 4; k++) {
                short hi = f2bf(vv[k]);
                hs[k] = hi;
                ls[k] = f2bf(vv[k] - bf2f_s(hi));
            }
            int boh = t * 256 + ((j4 * 8) ^ ((t & 7) << 4));
            *(short4v*)((char*)uplane + boh) = hs;
            *(short4v*)((char*)uplane + 4096 + boh) = ls;
        }
    }
    __syncthreads();

    // ---- B: in-proj via MFMA (hi*hi + lo*hi + hi*lo), dbuf prefetch ----
    {
        short8 ah[4], al[4];
        #pragma unroll
        for (int ks = 0; ks < 4; ks++) {
            int c = ks * 64 + lq * 16;
            int bo = lt * 256 + (c ^ ((lt & 7) << 4));
            ah[ks] = *(const short8*)((const char*)uplane + bo);
            al[ks] = *(const short8*)((const char*)uplane + 4096 + bo);
        }
        const short8* WF = (const short8*)(const void*)(S + OFF_WIN);
        const int fbase = (g * 32 + w * 8) * 512 + l;   // nt stride 512, ks stride 128, lo +64
        short8 wh[2][4], wl[2][4];
        #pragma unroll
        for (int ks = 0; ks < 4; ks++) {
            wh[0][ks] = WF[fbase + ks * 128];
            wl[0][ks] = WF[fbase + ks * 128 + 64];
        }
        #pragma unroll
        for (int ntl = 0; ntl < 8; ntl++) {
            int cur = ntl & 1, nxt = cur ^ 1;
            if (ntl < 7) {
                #pragma unroll
                for (int ks = 0; ks < 4; ks++) {
                    wh[nxt][ks] = WF[fbase + (ntl + 1) * 512 + ks * 128];
                    wl[nxt][ks] = WF[fbase + (ntl + 1) * 512 + ks * 128 + 64];
                }
            }
            float4v acc = {0.f, 0.f, 0.f, 0.f};
            #pragma unroll
            for (int ks = 0; ks < 4; ks++) {
                acc = __builtin_amdgcn_mfma_f32_16x16x32_bf16(ah[ks], wh[cur][ks], acc, 0, 0, 0);
                acc = __builtin_amdgcn_mfma_f32_16x16x32_bf16(al[ks], wh[cur][ks], acc, 0, 0, 0);
                acc = __builtin_amdgcn_mfma_f32_16x16x32_bf16(ah[ks], wl[cur][ks], acc, 0, 0, 0);
            }
            int n = (w * 8 + ntl) * 16 + lt;
            int t0 = lq * 4;
            if (n < 256) {          // a0 half (waves 0,1) -> f32 t-major
                #pragma unroll
                for (int r = 0; r < 4; r++) a0T[(t0 + r) * A0S + n] = acc[r];
            } else {                // z half (waves 2,3) -> bf16 t-major
                #pragma unroll
                for (int r = 0; r < 4; r++) zT[(t0 + r) * ZS + (n - 256)] = f2bf(acc[r]);
            }
        }
    }
    __syncthreads();

    // ---- C: depthwise conv(4) + silu (regs), publish xq plane [0,8K) ----
    float xq[16];
    {
        int e = tid, ge = g * 256 + e;
        float ar[16];
        #pragma unroll
        for (int t = 0; t < 16; t++) ar[t] = a0T[t * A0S + e];
        float w0 = S[OFF_CW1T + 0 * 1024 + ge];
        float w1 = S[OFF_CW1T + 1 * 1024 + ge];
        float w2 = S[OFF_CW1T + 2 * 1024 + ge];
        float w3 = S[OFF_CW1T + 3 * 1024 + ge];
        float bb = conv1_b[ge];
        #pragma unroll
        for (int t = 0; t < 16; t++) {
            float sa = bb + w3 * ar[t];
            if (t >= 1) sa += w2 * ar[t - 1];
            if (t >= 2) sa += w1 * ar[t - 2];
            if (t >= 3) sa += w0 * ar[t - 3];
            xq[t] = sa * (1.f / (1.f + __expf(-sa)));
        }
        #pragma unroll
        for (int t = 0; t < 16; t++) {
            int bo = t * 512 + ((e * 2) ^ ((t & 7) << 4));
            uplane[bo >> 1] = f2bf(xq[t]);
        }
    }
    __syncthreads();

    // ---- D: x-proj via MFMA (hi only), waves 0..2, weights preloaded ----
    if (w < 3) {
        const short8* WXF = (const short8*)(const void*)(S + OFF_WXP);
        short8 wx[8];
        #pragma unroll
        for (int ks = 0; ks < 8; ks++) wx[ks] = WXF[((g * 3 + w) * 8 + ks) * 64 + l];
        float4v acc = {0.f, 0.f, 0.f, 0.f};
        #pragma unroll
        for (int ks = 0; ks < 8; ks++) {
            int c = (ks * 32 + lq * 8) * 2;
            int bo = lt * 512 + (c ^ ((lt & 7) << 4));
            short8 a = *(const short8*)((const char*)uplane + bo);
            acc = __builtin_amdgcn_mfma_f32_16x16x32_bf16(a, wx[ks], acc, 0, 0, 0);
        }
        int r = w * 16 + lt;
        if (r < 40) {
            int t0 = lq * 4;
            #pragma unroll
            for (int rr = 0; rr < 4; rr++) {
                float v = acc[rr];
                int t = t0 + rr;
                if (r < 8) dtraw[t * 8 + r] = v;
                else if (r < 24) Bm[t * 20 + (r - 8)] = v;
                else Cm[t * 20 + (r - 24)] = v;
            }
        }
    }
    __syncthreads();

    // ---- E+F: dt + selective scan (regs), publish y plane [0,8K) ----
    {
        int e = tid, ge = g * 256 + e;
        float Av[16];
        #pragma unroll
        for (int n = 0; n < 16; n++) Av[n] = S[OFF_A2T + (g * 16 + n) * 256 + e];
        float dtw[8];
        #pragma unroll
        for (int r = 0; r < 8; r++) dtw[r] = S[OFF_DTWT + r * 1024 + ge];
        float dtbv = dt_b[ge];
        float Dv = Dp[ge];
        float h[16];
        #pragma unroll
        for (int n = 0; n < 16; n++) h[n] = 0.f;
        for (int t = 0; t < 16; t++) {
            const float4* q = (const float4*)&dtraw[t * 8];
            float4 q0 = q[0], q1 = q[1];
            float sa = dtbv + q0.x * dtw[0] + q0.y * dtw[1] + q0.z * dtw[2] + q0.w * dtw[3]
                            + q1.x * dtw[4] + q1.y * dtw[5] + q1.z * dtw[6] + q1.w * dtw[7];
            float dtv = fmaxf(sa, 0.f) + __logf(1.f + __expf(-fabsf(sa)));
            float Bl[16], Cl[16];
            {
                const float4* b4 = (const float4*)&Bm[t * 20];
                *(float4*)&Bl[0] = b4[0]; *(float4*)&Bl[4] = b4[1];
                *(float4*)&Bl[8] = b4[2]; *(float4*)&Bl[12] = b4[3];
                const float4* c4p = (const float4*)&Cm[t * 20];
                *(float4*)&Cl[0] = c4p[0]; *(float4*)&Cl[4] = c4p[1];
                *(float4*)&Cl[8] = c4p[2]; *(float4*)&Cl[12] = c4p[3];
            }
            float xv = xq[t];
            float dx = dtv * xv;
            float y = 0.f;
            #pragma unroll
            for (int n = 0; n < 16; n++) {
                h[n] = __expf(dtv * Av[n]) * h[n] + dx * Bl[n];
                y += h[n] * Cl[n];
            }
            y += Dv * xv;
            float zv = bf2f_s(zT[t * ZS + e]);
            y *= zv * (1.f / (1.f + __expf(-zv)));
            int bo = t * 512 + ((e * 2) ^ ((t & 7) << 4));
            uplane[bo >> 1] = f2bf(y);
        }
    }
    __syncthreads();

    // ---- G: out-proj via MFMA (hi only), 2 n-tiles/wave, prefetched ----
    {
        const short8* WOF = (const short8*)(const void*)(S + OFF_WOUT);
        const int gb = (g * 8 + w * 2) * 512 + l;   // nt stride 512, ks stride 64
        short8 wo[2][8];
        #pragma unroll
        for (int ks = 0; ks < 8; ks++) wo[0][ks] = WOF[gb + ks * 64];
        #pragma unroll
        for (int ntl = 0; ntl < 2; ntl++) {
            if (ntl == 0) {
                #pragma unroll
                for (int ks = 0; ks < 8; ks++) wo[1][ks] = WOF[gb + 512 + ks * 64];
            }
            float4v acc = {0.f, 0.f, 0.f, 0.f};
            #pragma unroll
            for (int ks = 0; ks < 8; ks++) {
                int c = (ks * 32 + lq * 8) * 2;
                int bo = lt * 512 + (c ^ ((lt & 7) << 4));
                short8 a = *(const short8*)((const char*)uplane + bo);
                acc = __builtin_amdgcn_mfma_f32_16x16x32_bf16(a, wo[ntl][ks], acc, 0, 0, 0);
            }
            int j = (w * 2 + ntl) * 16 + lt;
            int t0 = lq * 4;
            float* XM = S + OFF_XM + ((size_t)b * 96 + p * 16 + t0) * 512 + g * 128 + j;
            #pragma unroll
            for (int rr = 0; rr < 4; rr++) XM[rr * 512] = acc[rr];
        }
    }
}

// ---------------- kernel 4: final projection + de-normalize, 8 pos/block ----
#define NPO 8
__global__ __launch_bounds__(256) void k_out(float* S, float* __restrict__ out) {
    int bx = blockIdx.x, b = blockIdx.y;   // grid (12, 32)
    int tid = threadIdx.x;
    int c = tid & 31, part = tid >> 5;     // 8 parts x 64 d
    __shared__ __align__(16) float xls[NPO][512];
    __shared__ float red[8][NPO][32];
    __shared__ float smean[32], sstd[32];
    stats_load(S, b, tid, smean, nullptr, sstd);
    for (int i = tid; i < NPO * 512; i += 256) {
        int ip = i >> 9, d = i & 511;
        xls[ip][d] = S[OFF_XM + ((size_t)b * 96 + bx * NPO + ip) * 512 + d];
    }
    __syncthreads();
    const float* owT = S + OFF_OWT;
    float acc[NPO];
    #pragma unroll
    for (int ip = 0; ip < NPO; ip++) acc[ip] = 0.f;
    #pragma unroll 8
    for (int d = 0; d < 64; d++) {
        float w = owT[(part * 64 + d) * 32 + c];
        #pragma unroll
        for (int ip = 0; ip < NPO; ip++) acc[ip] += xls[ip][part * 64 + d] * w;
    }
    #pragma unroll
    for (int ip = 0; ip < NPO; ip++) red[part][ip][c] = acc[ip];
    __syncthreads();
    int ipo = tid >> 5;
    float Sm = 0.f;
    #pragma unroll
    for (int i = 0; i < 8; i++) Sm += red[i][ipo][c];
    int s = bx * NPO + ipo;
    out[((size_t)b * 96 + s) * 32 + c] = Sm * sstd[c] + smean[c];
}

extern "C" void kernel_launch(void* const* d_in, const int* in_sizes, int n_in,
                              void* d_out, int out_size, void* d_ws, size_t ws_size,
                              hipStream_t stream) {
    (void)in_sizes; (void)n_in; (void)out_size;
    const float* x_enc   = (const float*)d_in[0];
    const float* mark    = (const float*)d_in[1];
    const float* conv_w  = (const float*)d_in[4];
    const float* temp_w  = (const float*)d_in[5];
    const float* het_w   = (const float*)d_in[6];
    const float* het_b   = (const float*)d_in[7];
    const float* in_proj = (const float*)d_in[8];
    const float* conv1_w = (const float*)d_in[9];
    const float* conv1_b = (const float*)d_in[10];
    const float* xp_w    = (const float*)d_in[11];
    const float* dt_w    = (const float*)d_in[12];
    const float* dt_b    = (const float*)d_in[13];
    const float* A_log   = (const float*)d_in[14];
    const float* D_param = (const float*)d_in[15];
    const float* outp_w  = (const float*)d_in[16];
    const float* ow      = (const float*)d_in[17];
    float* out = (float*)d_out;

    float* S = (float*)d_ws;
    if (ws_size < (size_t)WS_FLOATS * sizeof(float)) {
        void* p = nullptr;
        hipGetSymbolAddress(&p, HIP_SYMBOL(g_fb));
        S = (float*)p;
    }

    k_prep<<<dim3(512), dim3(256), 0, stream>>>(S, x_enc, in_proj, outp_w, xp_w, het_w, ow,
                                                conv_w, temp_w, A_log, conv1_w, dt_w);
    k_e1<<<dim3(14, 32), dim3(256), 0, stream>>>(S, x_enc, mark, het_b);
    k_xc<<<dim3(12, 32), dim3(256), 0, stream>>>(S, x_enc, mark);
    k_mamba<<<dim3(6, 32, 4), dim3(256), 0, stream>>>(S, conv1_b, dt_b, D_param);
    k_out<<<dim3(12, 32), dim3(256), 0, stream>>>(S, out);
}